// Round 10
// baseline (474.078 us; speedup 1.0000x reference)
//
#include <hip/hip_runtime.h>
#include <hip/hip_bf16.h>

#define TT 2048
#define HD 2048
#define ID 2048
#define NE 8

typedef __attribute__((ext_vector_type(8))) short short8;
typedef __attribute__((ext_vector_type(4))) float f4;

__device__ __forceinline__ unsigned short b16(float f){
  union { __hip_bfloat16 b; unsigned short u; } x;
  x.b = __float2bfloat16(f);
  return x.u;
}
__device__ __forceinline__ unsigned pk2(float lo, float hi){
  return (unsigned)b16(lo) | ((unsigned)b16(hi) << 16);
}
__device__ __forceinline__ float gelu_t(float x){
  float y = 0.7978845608028654f * (x + 0.044715f * x * x * x);
  float t = 1.0f - 2.0f / (__expf(2.0f * y) + 1.0f);
  return 0.5f * x * (1.0f + t);
}
__device__ __forceinline__ void glds16(const void* g, void* l){
  __builtin_amdgcn_global_load_lds(
      (const __attribute__((address_space(1))) unsigned*)g,
      (__attribute__((address_space(3))) unsigned*)l, 16, 0, 0);
}
__device__ __forceinline__ void softbar(){
  asm volatile("s_waitcnt lgkmcnt(0)" ::: "memory");
  __builtin_amdgcn_s_barrier();
  __builtin_amdgcn_sched_barrier(0);
}
__device__ __forceinline__ int swzB(int n){ return (((n >> 2) & 7) ^ ((n & 3) << 1)) & 7; }

// ---------------- X fp32 -> bf16 ----------------
__global__ void k_cvtx(const float* __restrict__ X, __hip_bfloat16* __restrict__ Xb){
  int i = blockIdx.x * 256 + threadIdx.x;
  const f4* src = (const f4*)X + (size_t)i * 2;
  f4 a = src[0], b = src[1];
  uint4 o = { pk2(a[0],a[1]), pk2(a[2],a[3]), pk2(b[0],b[1]), pk2(b[2],b[3]) };
  ((uint4*)Xb)[i] = o;
}

// -------- W fp32 [e][k][n] -> bf16 [e][n][k] (transpose-convert), tile 128k x 64n --------
__global__ __launch_bounds__(256)
void k_cvtw(const float* __restrict__ Wg, const float* __restrict__ Wu,
            const float* __restrict__ Wd, __hip_bfloat16* __restrict__ Wb){
  __shared__ float s_t[128 * 65];
  const int bid = blockIdx.x;                 // 3 x 8 x 16kt x 32nt = 12288
  const int nt = bid & 31;
  const int kt = (bid >> 5) & 15;
  const int e  = (bid >> 9) & 7;
  const int m  = bid >> 12;
  const float* S = (m == 0 ? Wg : (m == 1 ? Wu : Wd))
                 + (size_t)e * HD * ID + (size_t)(kt * 128) * 2048 + nt * 64;
  __hip_bfloat16* D = Wb + (size_t)m * ((size_t)NE * 2048 * 2048)
                    + (size_t)(e * 2048 + nt * 64) * 2048 + kt * 128;
  const int tid = threadIdx.x;
  const int col4 = tid & 15, rq = tid >> 4;
#pragma unroll
  for (int i = 0; i < 8; i++){
    int row = i * 16 + rq;
    f4 v = *(const f4*)(S + (size_t)row * 2048 + col4 * 4);
#pragma unroll
    for (int j = 0; j < 4; j++) s_t[row * 65 + col4 * 4 + j] = v[j];
  }
  __syncthreads();
  const int n2 = tid >> 2, kc = (tid & 3) * 32;
  unsigned o[16];
#pragma unroll
  for (int a = 0; a < 16; a++){
    float lo = s_t[(kc + a * 2) * 65 + n2];
    float hi = s_t[(kc + a * 2 + 1) * 65 + n2];
    o[a] = pk2(lo, hi);
  }
  char* dp = (char*)(D + (size_t)n2 * 2048 + kc);
#pragma unroll
  for (int a = 0; a < 4; a++)
    *(uint4*)(dp + a * 16) = uint4{ o[a*4], o[a*4+1], o[a*4+2], o[a*4+3] };
}

// ---------------- routing ----------------
__global__ void k_route(const float* __restrict__ lg, const float* __restrict__ sc,
                        int* __restrict__ rid, float* __restrict__ rw){
  int t = blockIdx.x * blockDim.x + threadIdx.x;
  if (t >= TT) return;
  float l[NE];
#pragma unroll
  for (int e = 0; e < NE; e++) l[e] = lg[t * NE + e];
  float mx = l[0];
#pragma unroll
  for (int e = 1; e < NE; e++) mx = fmaxf(mx, l[e]);
  float p[NE];
#pragma unroll
  for (int e = 0; e < NE; e++) p[e] = __expf(l[e] - mx);
  int i0 = 0; float b0 = l[0];
#pragma unroll
  for (int e = 1; e < NE; e++) if (l[e] > b0){ b0 = l[e]; i0 = e; }
  int i1 = -1; float b1 = -1e30f;
#pragma unroll
  for (int e = 0; e < NE; e++) if (e != i0 && l[e] > b1){ b1 = l[e]; i1 = e; }
  float p0 = p[i0], p1 = p[i1];
  float rn = p0 + p1; rn = (rn > 0.f) ? rn : 1.f;
  rw[t*2]   = p0 / rn * sc[i0];
  rw[t*2+1] = p1 / rn * sc[i1];
  rid[t*2]  = i0;
  rid[t*2+1]= i1;
}

// ---------------- deterministic per-expert compaction ----------------
__global__ void k_lists(const int* __restrict__ rid, const float* __restrict__ rw,
                        int* __restrict__ row_tok, float* __restrict__ row_w,
                        int* __restrict__ off){
  int lane = threadIdx.x;            // 64 threads
  int ids[64]; float wv[64];
#pragma unroll
  for (int i = 0; i < 64; i++) ids[i] = rid[i * 64 + lane];
#pragma unroll
  for (int i = 0; i < 64; i++) wv[i] = rw[i * 64 + lane];
  int cnt[NE];
#pragma unroll
  for (int e = 0; e < NE; e++) cnt[e] = 0;
#pragma unroll
  for (int i = 0; i < 64; i++){
#pragma unroll
    for (int e = 0; e < NE; e++)
      cnt[e] += __popcll(__ballot(ids[i] == e));
  }
  int offs[NE + 1]; offs[0] = 0;
#pragma unroll
  for (int e = 0; e < NE; e++) offs[e + 1] = offs[e] + cnt[e];
  if (lane == 0){
#pragma unroll
    for (int e = 0; e <= NE; e++) off[e] = offs[e];
  }
  int run[NE];
#pragma unroll
  for (int e = 0; e < NE; e++) run[e] = offs[e];
  unsigned long long ltm = (1ULL << lane) - 1ULL;
#pragma unroll
  for (int i = 0; i < 64; i++){
    int id = ids[i];
    int tok = (i * 64 + lane) >> 1;
#pragma unroll
    for (int e = 0; e < NE; e++){
      unsigned long long m = __ballot(id == e);
      if (id == e){
        int pos = run[e] + __popcll(m & ltm);
        row_tok[pos] = tok;
        row_w[pos]   = wv[i];
      }
      run[e] += __popcll(m);
    }
  }
}

// ================= FAST PATH: 512 thr, 256m x 128n, BK=64, counted-vmcnt 2-phase =================
// LDS rows = 128B (8 slots x 16B); swizzle slot' = slot ^ (row&7) (m201 st_16x32 form).
// Grid decomposition: e OUTERMOST, mt INNERMOST -> heavy/partial/dead blocks interleave across
// XCDs under round-robin dispatch (kills the per-XCD tail from expert pinning).

// -------- gate+up: dual output, wave = 128m x 32n x {g,u}: 64 MFMA / wave / iter --------
__global__ __launch_bounds__(512, 2)
void k_gateup_f(const __hip_bfloat16* __restrict__ Xb, const __hip_bfloat16* __restrict__ Wtg,
                const __hip_bfloat16* __restrict__ Wtu, const int* __restrict__ row_tok,
                const int* __restrict__ off, __hip_bfloat16* __restrict__ hbuf){
  __shared__ __align__(16) char sA[2][32768];   // [256 m][64 k] bf16, swizzled
  __shared__ __align__(16) char sBg[2][16384];  // [128 n][64 k] bf16
  __shared__ __align__(16) char sBu[2][16384];
  __shared__ int s_tok[256];

  const int bid = blockIdx.x;           // 512 = 8e(outer) x 16nt x 4mt(inner)
  const int e  = bid >> 6;
  const int nt = (bid >> 2) & 15;
  const int mt = bid & 3;
  const int o0 = off[e], cnt = off[e + 1] - o0;
  if (mt * 256 >= cnt) return;
  const int p0 = o0 + mt * 256;
  const int cntL = min(256, cnt - mt * 256);
  const int tid = threadIdx.x;
  const int wid = tid >> 6, lane = tid & 63;

  if (tid < 256) s_tok[tid] = row_tok[min(p0 + tid, TT*2 - 1)];
  __syncthreads();

  // staging: chunk = 1KB = 8 rows x 128B; lane l -> row l>>3, slot l&7
  const int sw = (((lane & 7) ^ (lane >> 3)) & 7) << 4;   // inverse swizzle on source
  const char* asrc[4];
#pragma unroll
  for (int i = 0; i < 4; i++){
    int r = (wid * 4 + i) * 8 + (lane >> 3);              // 0..255
    asrc[i] = (const char*)Xb + (size_t)s_tok[r] * 4096 + sw;
  }
  const char* gsrc[2]; const char* usrc[2];
#pragma unroll
  for (int i = 0; i < 2; i++){
    int n = (wid * 2 + i) * 8 + (lane >> 3);              // 0..127
    size_t rowb = (size_t)(e * 2048 + nt * 128 + n) * 4096;
    gsrc[i] = (const char*)Wtg + rowb + sw;
    usrc[i] = (const char*)Wtu + rowb + sw;
  }
  const int wm = wid >> 2, wn = wid & 3;        // 2x4 waves: wave = 128m x 32n (dual)
  const int kg = lane >> 4, ln = lane & 15;
  int aoff[8], boff[2];
#pragma unroll
  for (int f = 0; f < 8; f++){
    int m = wm * 128 + f * 16 + ln;
    aoff[f] = m * 128 + (((kg ^ (m & 7)) & 7) << 4);
  }
#pragma unroll
  for (int f = 0; f < 2; f++){
    int n = wn * 32 + f * 16 + ln;
    boff[f] = n * 128 + (((kg ^ (n & 7)) & 7) << 4);
  }

  f4 accg[8][2], accu[8][2];
#pragma unroll
  for (int a = 0; a < 8; a++)
#pragma unroll
    for (int b = 0; b < 2; b++){ accg[a][b] = f4{0,0,0,0}; accu[a][b] = f4{0,0,0,0}; }

#define GUSTAGE(buf, kt) do{ const int _o = (kt) * 128;                          \
    _Pragma("unroll") for (int i = 0; i < 4; i++)                                \
      glds16(asrc[i] + _o, &sA[buf][(wid * 4 + i) * 1024]);                      \
    _Pragma("unroll") for (int i = 0; i < 2; i++)                                \
      glds16(gsrc[i] + _o, &sBg[buf][(wid * 2 + i) * 1024]);                     \
    _Pragma("unroll") for (int i = 0; i < 2; i++)                                \
      glds16(usrc[i] + _o, &sBu[buf][(wid * 2 + i) * 1024]); }while(0)

  GUSTAGE(0, 0);                                 // 8 loads/wave in flight
  for (int kt = 0; kt < 32; ++kt){
    const int cur = kt & 1;
    if (kt + 1 < 32){
      GUSTAGE(cur ^ 1, kt + 1);                  // +8 ; buf safe: prev bottom barrier
      asm volatile("s_waitcnt vmcnt(8)" ::: "memory");   // tile kt landed, kt+1 in flight
    } else {
      asm volatile("s_waitcnt vmcnt(0)" ::: "memory");
    }
    __builtin_amdgcn_s_barrier();
    __builtin_amdgcn_sched_barrier(0);
    const char* A = &sA[cur][0];
    const char* G = &sBg[cur][0];
    const char* U = &sBu[cur][0];
#pragma unroll
    for (int ks = 0; ks < 2; ks++){
      const int kx = ks * 64;                    // slot' ^= 4 -> byte ^ 0x40
      short8 bg0 = *(const short8*)(G + (boff[0] ^ kx));
      short8 bg1 = *(const short8*)(G + (boff[1] ^ kx));
      short8 bu0 = *(const short8*)(U + (boff[0] ^ kx));
      short8 bu1 = *(const short8*)(U + (boff[1] ^ kx));
#pragma unroll
      for (int fm = 0; fm < 8; fm++){
        short8 af = *(const short8*)(A + (aoff[fm] ^ kx));
        accg[fm][0] = __builtin_amdgcn_mfma_f32_16x16x32_bf16(af, bg0, accg[fm][0], 0, 0, 0);
        accg[fm][1] = __builtin_amdgcn_mfma_f32_16x16x32_bf16(af, bg1, accg[fm][1], 0, 0, 0);
        accu[fm][0] = __builtin_amdgcn_mfma_f32_16x16x32_bf16(af, bu0, accu[fm][0], 0, 0, 0);
        accu[fm][1] = __builtin_amdgcn_mfma_f32_16x16x32_bf16(af, bu1, accu[fm][1], 0, 0, 0);
      }
    }
    __builtin_amdgcn_sched_barrier(0);
    asm volatile("s_waitcnt lgkmcnt(0)" ::: "memory");
    __builtin_amdgcn_s_barrier();                // all waves done reading buf[cur]
    __builtin_amdgcn_sched_barrier(0);
  }
#undef GUSTAGE
  // epilogue: h = gelu(g)*u -> bf16
#pragma unroll
  for (int fm = 0; fm < 8; fm++){
#pragma unroll
    for (int r = 0; r < 4; r++){
      int row = wm * 128 + fm * 16 + (lane >> 4) * 4 + r;
      if (row < cntL){
        size_t base = (size_t)(p0 + row) * ID + (size_t)nt * 128 + wn * 32 + ln;
#pragma unroll
        for (int fn = 0; fn < 2; fn++){
          float g = accg[fm][fn][r];
          float u = accu[fm][fn][r];
          hbuf[base + fn * 16] = __float2bfloat16(gelu_t(g) * u);
        }
      }
    }
  }
}

// -------- down: 256m x 128n single, wave = 128m x 32n + weighted atomic scatter --------
__global__ __launch_bounds__(512, 2)
void k_down_f(const __hip_bfloat16* __restrict__ hbuf, const __hip_bfloat16* __restrict__ Wtd,
              const int* __restrict__ row_tok, const float* __restrict__ row_w,
              const int* __restrict__ off, float* __restrict__ out){
  __shared__ __align__(16) char sA[2][32768];   // [256 m][64 k]
  __shared__ __align__(16) char sB[2][16384];   // [128 n][64 k]
  __shared__ int s_tok[256];
  __shared__ float s_w[256];

  const int bid = blockIdx.x;           // 512 = 8e(outer) x 16nt x 4mt(inner)
  const int e  = bid >> 6;
  const int nt = (bid >> 2) & 15;
  const int mt = bid & 3;
  const int o0 = off[e], cnt = off[e + 1] - o0;
  if (mt * 256 >= cnt) return;
  const int p0 = o0 + mt * 256;
  const int cntL = min(256, cnt - mt * 256);
  const int tid = threadIdx.x;
  const int wid = tid >> 6, lane = tid & 63;

  if (tid < 256){
    int p = min(p0 + tid, TT*2 - 1);
    s_tok[tid] = row_tok[p];
    s_w[tid]   = row_w[p];
  }
  __syncthreads();

  const int sw = (((lane & 7) ^ (lane >> 3)) & 7) << 4;
  const char* asrc[4]; const char* bsrc[2];
#pragma unroll
  for (int i = 0; i < 4; i++){
    int r = (wid * 4 + i) * 8 + (lane >> 3);
    int p = min(p0 + r, TT*2 - 1);
    asrc[i] = (const char*)hbuf + (size_t)p * 4096 + sw;
  }
#pragma unroll
  for (int i = 0; i < 2; i++){
    int n = (wid * 2 + i) * 8 + (lane >> 3);
    bsrc[i] = (const char*)Wtd + (size_t)(e * 2048 + nt * 128 + n) * 4096 + sw;
  }
  const int wm = wid >> 2, wn = wid & 3;
  const int kg = lane >> 4, ln = lane & 15;
  int aoff[8], boff[2];
#pragma unroll
  for (int f = 0; f < 8; f++){
    int m = wm * 128 + f * 16 + ln;
    aoff[f] = m * 128 + (((kg ^ (m & 7)) & 7) << 4);
  }
#pragma unroll
  for (int f = 0; f < 2; f++){
    int n = wn * 32 + f * 16 + ln;
    boff[f] = n * 128 + (((kg ^ (n & 7)) & 7) << 4);
  }

  f4 acc[8][2];
#pragma unroll
  for (int a = 0; a < 8; a++)
#pragma unroll
    for (int b = 0; b < 2; b++) acc[a][b] = f4{0,0,0,0};

#define DSTAGE(buf, kt) do{ const int _o = (kt) * 128;                           \
    _Pragma("unroll") for (int i = 0; i < 4; i++)                                \
      glds16(asrc[i] + _o, &sA[buf][(wid * 4 + i) * 1024]);                      \
    _Pragma("unroll") for (int i = 0; i < 2; i++)                                \
      glds16(bsrc[i] + _o, &sB[buf][(wid * 2 + i) * 1024]); }while(0)

  DSTAGE(0, 0);
  for (int kt = 0; kt < 32; ++kt){
    const int cur = kt & 1;
    if (kt + 1 < 32){
      DSTAGE(cur ^ 1, kt + 1);
      asm volatile("s_waitcnt vmcnt(6)" ::: "memory");
    } else {
      asm volatile("s_waitcnt vmcnt(0)" ::: "memory");
    }
    __builtin_amdgcn_s_barrier();
    __builtin_amdgcn_sched_barrier(0);
    const char* A = &sA[cur][0];
    const char* B = &sB[cur][0];
#pragma unroll
    for (int ks = 0; ks < 2; ks++){
      const int kx = ks * 64;
      short8 b0 = *(const short8*)(B + (boff[0] ^ kx));
      short8 b1 = *(const short8*)(B + (boff[1] ^ kx));
#pragma unroll
      for (int fm = 0; fm < 8; fm++){
        short8 af = *(const short8*)(A + (aoff[fm] ^ kx));
        acc[fm][0] = __builtin_amdgcn_mfma_f32_16x16x32_bf16(af, b0, acc[fm][0], 0, 0, 0);
        acc[fm][1] = __builtin_amdgcn_mfma_f32_16x16x32_bf16(af, b1, acc[fm][1], 0, 0, 0);
      }
    }
    __builtin_amdgcn_sched_barrier(0);
    asm volatile("s_waitcnt lgkmcnt(0)" ::: "memory");
    __builtin_amdgcn_s_barrier();
    __builtin_amdgcn_sched_barrier(0);
  }
#undef DSTAGE
#pragma unroll
  for (int fm = 0; fm < 8; fm++){
#pragma unroll
    for (int r = 0; r < 4; r++){
      int row = wm * 128 + fm * 16 + (lane >> 4) * 4 + r;
      if (row < cntL){
        int tok = s_tok[row];
        float w = s_w[row];
        float* ob = out + (size_t)tok * HD + (size_t)nt * 128 + wn * 32 + ln;
#pragma unroll
        for (int fn = 0; fn < 2; fn++)
          atomicAdd(ob + fn * 16, acc[fm][fn][r] * w);
      }
    }
  }
}

// ================= FALLBACK PATH (round-3 kernels, known-good) =================

__global__ __launch_bounds__(256, 3)
void k_gateup_r3(const __hip_bfloat16* __restrict__ Xb, const float* __restrict__ Wg,
                 const float* __restrict__ Wu, const int* __restrict__ row_tok,
                 const int* __restrict__ off, __hip_bfloat16* __restrict__ hbuf){
  __shared__ __align__(16) char sA[2][16384];
  __shared__ __align__(16) char sBg[8192];
  __shared__ __align__(16) char sBu[8192];
  __shared__ int s_tok[128];

  const int bid = blockIdx.x;
  const int e  = bid & 7;
  const int mt = (bid >> 3) & 7;
  const int nt = bid >> 6;
  const int o0 = off[e], cnt = off[e + 1] - o0;
  if (mt * 128 >= cnt) return;
  const int p0 = o0 + mt * 128;
  const int cntL = min(128, cnt - mt * 128);
  const int tid = threadIdx.x;
  const int wid = tid >> 6, lane = tid & 63;

  if (tid < 128) s_tok[tid] = row_tok[min(p0 + tid, TT*2 - 1)];
  __syncthreads();

  const char* asrc[4];
#pragma unroll
  for (int i = 0; i < 4; i++){
    int c = wid * 4 + i;
    int r = c * 8 + (lane >> 3);
    asrc[i] = (const char*)Xb + (size_t)s_tok[r] * (HD * 2)
            + ((((lane & 7) ^ (lane >> 3)) & 7) << 4);
  }
  const int n0 = (tid & 15) * 4;
  const int k0 = (tid >> 4) * 4;
  const size_t wb = (size_t)e * HD * ID + (size_t)k0 * ID + (size_t)nt * 64 + n0;
  const float* gsrc = Wg + wb;
  const float* usrc = Wu + wb;
  int bw[4];
#pragma unroll
  for (int j = 0; j < 4; j++)
    bw[j] = (n0 + j) * 128 + ((((k0 >> 3) ^ (tid & 7) ^ (j << 1)) & 7) << 4) + ((k0 & 4) << 1);

  const int wm = wid >> 1, wn = wid & 1;
  const int kg = lane >> 4, ln = lane & 15;
  int aoff[2][4], boff[2][2];
#pragma unroll
  for (int ks = 0; ks < 2; ks++){
    int qs = ks * 4 + kg;
#pragma unroll
    for (int f = 0; f < 4; f++){
      int m = wm * 64 + f * 16 + ln;
      aoff[ks][f] = m * 128 + (((qs ^ (ln & 7)) & 7) << 4);
    }
#pragma unroll
    for (int f = 0; f < 2; f++){
      int n = wn * 32 + f * 16 + ln;
      boff[ks][f] = n * 128 + (((qs ^ swzB(n)) & 7) << 4);
    }
  }

  f4 accg[4][2], accu[4][2];
#pragma unroll
  for (int a = 0; a < 4; a++)
#pragma unroll
    for (int b = 0; b < 2; b++){ accg[a][b] = f4{0,0,0,0}; accu[a][b] = f4{0,0,0,0}; }

#pragma unroll
  for (int i = 0; i < 4; i++) glds16(asrc[i], &sA[0][(wid * 4 + i) * 1024]);
  f4 g0, g1, g2, g3, u0, u1, u2, u3;
  { const f4* p = (const f4*)gsrc; g0 = p[0]; g1 = p[ID/4]; g2 = p[ID/2]; g3 = p[3*ID/4];
    const f4* q = (const f4*)usrc; u0 = q[0]; u1 = q[ID/4]; u2 = q[ID/2]; u3 = q[3*ID/4]; }

  for (int kt = 0; kt < 32; ++kt){
    softbar();
    if (kt + 1 < 32){
      char* dst = &sA[(kt + 1) & 1][0] + (wid * 4) * 1024;
#pragma unroll
      for (int i = 0; i < 4; i++) glds16(asrc[i] + (size_t)(kt + 1) * 128, dst + i * 1024);
    }
#pragma unroll
    for (int j = 0; j < 4; j++){
      *(uint2*)(sBg + bw[j]) = uint2{ pk2(g0[j], g1[j]), pk2(g2[j], g3[j]) };
      *(uint2*)(sBu + bw[j]) = uint2{ pk2(u0[j], u1[j]), pk2(u2[j], u3[j]) };
    }
    softbar();
    if (kt + 1 < 32){
      const f4* p = (const f4*)(gsrc + (size_t)(kt + 1) * 64 * ID);
      g0 = p[0]; g1 = p[ID/4]; g2 = p[ID/2]; g3 = p[3*ID/4];
      const f4* q = (const f4*)(usrc + (size_t)(kt + 1) * 64 * ID);
      u0 = q[0]; u1 = q[ID/4]; u2 = q[ID/2]; u3 = q[3*ID/4];
    }
    const char* A = &sA[kt & 1][0];
#pragma unroll
    for (int ks = 0; ks < 2; ks++){
      short8 af[4];
#pragma unroll
      for (int f = 0; f < 4; f++) af[f] = *(const short8*)(A + aoff[ks][f]);
#pragma unroll
      for (int fn = 0; fn < 2; fn++){
        short8 bg = *(const short8*)(sBg + boff[ks][fn]);
        short8 bu = *(const short8*)(sBu + boff[ks][fn]);
#pragma unroll
        for (int fm = 0; fm < 4; fm++){
          accg[fm][fn] = __builtin_amdgcn_mfma_f32_16x16x32_bf16(af[fm], bg, accg[fm][fn], 0, 0, 0);
          accu[fm][fn] = __builtin_amdgcn_mfma_f32_16x16x32_bf16(af[fm], bu, accu[fm][fn], 0, 0, 0);
        }
      }
    }
  }
#pragma unroll
  for (int fm = 0; fm < 4; fm++){
#pragma unroll
    for (int r = 0; r < 4; r++){
      int row = wm * 64 + fm * 16 + (lane >> 4) * 4 + r;
      if (row < cntL){
        size_t base = (size_t)(p0 + row) * ID + (size_t)nt * 64 + wn * 32 + ln;
#pragma unroll
        for (int fn = 0; fn < 2; fn++){
          float g = accg[fm][fn][r];
          float u = accu[fm][fn][r];
          hbuf[base + fn * 16] = __float2bfloat16(gelu_t(g) * u);
        }
      }
    }
  }
}

__global__ __launch_bounds__(256, 3)
void k_down_r3(const __hip_bfloat16* __restrict__ hbuf, const float* __restrict__ Wd,
               const int* __restrict__ row_tok, const float* __restrict__ row_w,
               const int* __restrict__ off, float* __restrict__ out){
  __shared__ __align__(16) char sA[2][16384];
  __shared__ __align__(16) char sB[16384];
  __shared__ int s_tok[128];
  __shared__ float s_w[128];

  const int bid = blockIdx.x;
  const int e  = bid & 7;
  const int mt = (bid >> 3) & 7;
  const int nt = bid >> 6;
  const int o0 = off[e], cnt = off[e + 1] - o0;
  if (mt * 128 >= cnt) return;
  const int p0 = o0 + mt * 128;
  const int cntL = min(128, cnt - mt * 128);
  const int tid = threadIdx.x;
  const int wid = tid >> 6, lane = tid & 63;

  if (tid < 128){
    int p = min(p0 + tid, TT*2 - 1);
    s_tok[tid] = row_tok[p];
    s_w[tid]   = row_w[p];
  }
  __syncthreads();

  const char* asrc[4];
#pragma unroll
  for (int i = 0; i < 4; i++){
    int c = wid * 4 + i;
    int r = c * 8 + (lane >> 3);
    int p = min(p0 + r, TT*2 - 1);
    asrc[i] = (const char*)hbuf + (size_t)p * (ID * 2)
            + ((((lane & 7) ^ (lane >> 3)) & 7) << 4);
  }
  const int n0 = (tid & 31) * 4;
  const int k0 = (tid >> 5) * 8;
  const float* bsrc = Wd + (size_t)e * ID * HD + (size_t)k0 * HD + (size_t)nt * 128 + n0;
  int bw[4];
#pragma unroll
  for (int j = 0; j < 4; j++)
    bw[j] = (n0 + j) * 128 + ((((k0 >> 3) ^ (tid & 7) ^ (j << 1)) & 7) << 4);

  const int wm = wid >> 1, wn = wid & 1;
  const int kg = lane >> 4, ln = lane & 15;
  int aoff[2][4], boff[2][4];
#pragma unroll
  for (int ks = 0; ks < 2; ks++){
    int qs = ks * 4 + kg;
#pragma unroll
    for (int f = 0; f < 4; f++){
      int m = wm * 64 + f * 16 + ln;
      aoff[ks][f] = m * 128 + (((qs ^ (ln & 7)) & 7) << 4);
      int n = wn * 64 + f * 16 + ln;
      boff[ks][f] = n * 128 + (((qs ^ swzB(n)) & 7) << 4);
    }
  }

  f4 acc[4][4];
#pragma unroll
  for (int a = 0; a < 4; a++)
#pragma unroll
    for (int b = 0; b < 4; b++) acc[a][b] = f4{0,0,0,0};

#pragma unroll
  for (int i = 0; i < 4; i++) glds16(asrc[i], &sA[0][(wid * 4 + i) * 1024]);
  f4 r0, r1, r2, r3, r4, r5, r6, r7;
  { const f4* p = (const f4*)bsrc;
    r0 = p[0]; r1 = p[HD/4]; r2 = p[HD/2]; r3 = p[3*HD/4];
    r4 = p[HD]; r5 = p[5*HD/4]; r6 = p[3*HD/2]; r7 = p[7*HD/4]; }

  for (int kt = 0; kt < 32; ++kt){
    softbar();
    if (kt + 1 < 32){
      char* dst = &sA[(kt + 1) & 1][0] + (wid * 4) * 1024;
#pragma unroll
      for (int i = 0; i < 4; i++) glds16(asrc[i] + (size_t)(kt + 1) * 128, dst + i * 1024);
    }
#pragma unroll
    for (int j = 0; j < 4; j++){
      *(uint4*)(sB + bw[j]) = uint4{ pk2(r0[j], r1[j]), pk2(r2[j], r3[j]),
                                     pk2(r4[j], r5[j]), pk2(r6[j], r7[j]) };
    }
    softbar();
    if (kt + 1 < 32){
      const f4* p = (const f4*)(bsrc + (size_t)(kt + 1) * 64 * HD);
      r0 = p[0]; r1 = p[HD/4]; r2 = p[HD/2]; r3 = p[3*HD/4];
      r4 = p[HD]; r5 = p[5*HD/4]; r6 = p[3*HD/2]; r7 = p[7*HD/4];
    }
    const char* A = &sA[kt & 1][0];
#pragma unroll
    for (int ks = 0; ks < 2; ks++){
      short8 af[4];
#pragma unroll
      for (int f = 0; f < 4; f++) af[f] = *(const short8*)(A + aoff[ks][f]);
#pragma unroll
      for (int fn = 0; fn < 4; fn++){
        short8 bf = *(const short8*)(sB + boff[ks][fn]);
#pragma unroll
        for (int fm = 0; fm < 4; fm++)
          acc[fm][fn] = __builtin_amdgcn_mfma_f32_16x16x32_bf16(af[fm], bf, acc[fm][fn], 0, 0, 0);
      }
    }
  }
#pragma unroll
  for (int fm = 0; fm < 4; fm++){
#pragma unroll
    for (int r = 0; r < 4; r++){
      int row = wm * 64 + fm * 16 + (lane >> 4) * 4 + r;
      if (row < cntL){
        int tok = s_tok[row];
        float w = s_w[row];
        float* ob = out + (size_t)tok * HD + (size_t)nt * 128 + wn * 64 + ln;
#pragma unroll
        for (int fn = 0; fn < 4; fn++)
          atomicAdd(ob + fn * 16, acc[fm][fn][r] * w);
      }
    }
  }
}

extern "C" void kernel_launch(void* const* d_in, const int* in_sizes, int n_in,
                              void* d_out, int out_size, void* d_ws, size_t ws_size,
                              hipStream_t stream){
  (void)in_sizes; (void)n_in; (void)out_size;
  const float* X  = (const float*)d_in[0];
  const float* RL = (const float*)d_in[1];
  const float* SC = (const float*)d_in[2];
  const float* Wg = (const float*)d_in[3];
  const float* Wu = (const float*)d_in[4];
  const float* Wd = (const float*)d_in[5];
  float* out = (float*)d_out;

  char* ws = (char*)d_ws;
  int*   rid     = (int*)(ws);
  float* rw      = (float*)(ws + 16384);
  int*   row_tok = (int*)(ws + 32768);
  float* row_w   = (float*)(ws + 49152);
  int*   off     = (int*)(ws + 65536);
  __hip_bfloat16* hbuf = (__hip_bfloat16*)(ws + 66560);                      // 16 MiB
  __hip_bfloat16* Xb   = (__hip_bfloat16*)(ws + 66560 + 16777216ull);        // 8 MiB
  __hip_bfloat16* Wb   = (__hip_bfloat16*)(ws + 66560 + 16777216ull + 8388608ull);
  const size_t WME = (size_t)NE * 2048 * 2048;                               // elems per tensor
  const size_t need = 66560ull + 16777216ull + 8388608ull + 3ull * WME * 2ull;

  hipMemsetAsync(d_out, 0, (size_t)TT * HD * sizeof(float), stream);
  k_cvtx <<<2048, 256, 0, stream>>>(X, Xb);
  k_route<<<TT / 256, 256, 0, stream>>>(RL, SC, rid, rw);
  k_lists<<<1, 64, 0, stream>>>(rid, rw, row_tok, row_w, off);

  if (ws_size >= need){
    k_cvtw<<<12288, 256, 0, stream>>>(Wg, Wu, Wd, Wb);
    k_gateup_f<<<512, 512, 0, stream>>>(Xb, Wb, Wb + WME, row_tok, off, hbuf);
    k_down_f  <<<512, 512, 0, stream>>>(hbuf, Wb + 2 * WME, row_tok, row_w, off, out);
  } else {
    k_gateup_r3<<<2048, 256, 0, stream>>>(Xb, Wg, Wu, row_tok, off, hbuf);
    k_down_r3  <<<1024, 256, 0, stream>>>(hbuf, Wd, row_tok, row_w, off, out);
  }
}

// Round 11
// 359.587 us; speedup vs baseline: 1.3184x; 1.3184x over previous
//
#include <hip/hip_runtime.h>
#include <hip/hip_bf16.h>

#define TT 2048
#define HD 2048
#define ID 2048
#define NE 8

typedef __attribute__((ext_vector_type(8))) short short8;
typedef __attribute__((ext_vector_type(4))) float f4;

__device__ __forceinline__ unsigned short b16(float f){
  union { __hip_bfloat16 b; unsigned short u; } x;
  x.b = __float2bfloat16(f);
  return x.u;
}
__device__ __forceinline__ unsigned pk2(float lo, float hi){
  return (unsigned)b16(lo) | ((unsigned)b16(hi) << 16);
}
__device__ __forceinline__ float gelu_t(float x){
  float y = 0.7978845608028654f * (x + 0.044715f * x * x * x);
  float t = 1.0f - 2.0f / (__expf(2.0f * y) + 1.0f);
  return 0.5f * x * (1.0f + t);
}
__device__ __forceinline__ void glds16(const void* g, void* l){
  __builtin_amdgcn_global_load_lds(
      (const __attribute__((address_space(1))) unsigned*)g,
      (__attribute__((address_space(3))) unsigned*)l, 16, 0, 0);
}
__device__ __forceinline__ void softbar(){
  asm volatile("s_waitcnt lgkmcnt(0)" ::: "memory");
  __builtin_amdgcn_s_barrier();
  __builtin_amdgcn_sched_barrier(0);
}
__device__ __forceinline__ int swzB(int n){ return (((n >> 2) & 7) ^ ((n & 3) << 1)) & 7; }

// ---------------- X fp32 -> bf16 ----------------
__global__ void k_cvtx(const float* __restrict__ X, __hip_bfloat16* __restrict__ Xb){
  int i = blockIdx.x * 256 + threadIdx.x;
  const f4* src = (const f4*)X + (size_t)i * 2;
  f4 a = src[0], b = src[1];
  uint4 o = { pk2(a[0],a[1]), pk2(a[2],a[3]), pk2(b[0],b[1]), pk2(b[2],b[3]) };
  ((uint4*)Xb)[i] = o;
}

// -------- W fp32 [e][k][n] -> bf16 transposed layouts --------
// m=0 (gate), m=1 (up): Wgu[e][n'][k], n' = (n>>5)*64 + (n&31) + m*32  (32-col g/u interleave)
// m=2 (down):           Wdt[e][n][k]
__global__ __launch_bounds__(256)
void k_cvtw(const float* __restrict__ Wg, const float* __restrict__ Wu,
            const float* __restrict__ Wd, __hip_bfloat16* __restrict__ Wb){
  __shared__ float s_t[128 * 65];
  const int bid = blockIdx.x;                 // 3 x 8 x 16kt x 32nt = 12288
  const int nt = bid & 31;
  const int kt = (bid >> 5) & 15;
  const int e  = (bid >> 9) & 7;
  const int m  = bid >> 12;
  const float* S = (m == 0 ? Wg : (m == 1 ? Wu : Wd))
                 + (size_t)e * HD * ID + (size_t)(kt * 128) * 2048 + nt * 64;
  const int tid = threadIdx.x;
  const int col4 = tid & 15, rq = tid >> 4;
#pragma unroll
  for (int i = 0; i < 8; i++){
    int row = i * 16 + rq;
    f4 v = *(const f4*)(S + (size_t)row * 2048 + col4 * 4);
#pragma unroll
    for (int j = 0; j < 4; j++) s_t[row * 65 + col4 * 4 + j] = v[j];
  }
  __syncthreads();
  const int n2 = tid >> 2, kc = (tid & 3) * 32;
  unsigned o[16];
#pragma unroll
  for (int a = 0; a < 16; a++){
    float lo = s_t[(kc + a * 2) * 65 + n2];
    float hi = s_t[(kc + a * 2 + 1) * 65 + n2];
    o[a] = pk2(lo, hi);
  }
  size_t drow;
  if (m < 2){
    int ng = nt * 64 + n2;
    drow = (size_t)e * 4096 + (ng >> 5) * 64 + (ng & 31) + m * 32;       // gu region
  } else {
    drow = (size_t)8 * 4096 + (size_t)e * 2048 + nt * 64 + n2;           // d region after gu
  }
  char* dp = (char*)(Wb + drow * 2048 + (size_t)kt * 128 + kc);
#pragma unroll
  for (int a = 0; a < 4; a++)
    *(uint4*)(dp + a * 16) = uint4{ o[a*4], o[a*4+1], o[a*4+2], o[a*4+3] };
}

// ---------------- routing ----------------
__global__ void k_route(const float* __restrict__ lg, const float* __restrict__ sc,
                        int* __restrict__ rid, float* __restrict__ rw){
  int t = blockIdx.x * blockDim.x + threadIdx.x;
  if (t >= TT) return;
  float l[NE];
#pragma unroll
  for (int e = 0; e < NE; e++) l[e] = lg[t * NE + e];
  float mx = l[0];
#pragma unroll
  for (int e = 1; e < NE; e++) mx = fmaxf(mx, l[e]);
  float p[NE];
#pragma unroll
  for (int e = 0; e < NE; e++) p[e] = __expf(l[e] - mx);
  int i0 = 0; float b0 = l[0];
#pragma unroll
  for (int e = 1; e < NE; e++) if (l[e] > b0){ b0 = l[e]; i0 = e; }
  int i1 = -1; float b1 = -1e30f;
#pragma unroll
  for (int e = 0; e < NE; e++) if (e != i0 && l[e] > b1){ b1 = l[e]; i1 = e; }
  float p0 = p[i0], p1 = p[i1];
  float rn = p0 + p1; rn = (rn > 0.f) ? rn : 1.f;
  rw[t*2]   = p0 / rn * sc[i0];
  rw[t*2+1] = p1 / rn * sc[i1];
  rid[t*2]  = i0;
  rid[t*2+1]= i1;
}

// ---------------- deterministic per-expert compaction ----------------
__global__ void k_lists(const int* __restrict__ rid, const float* __restrict__ rw,
                        int* __restrict__ row_tok, float* __restrict__ row_w,
                        int* __restrict__ off){
  int lane = threadIdx.x;            // 64 threads
  int ids[64]; float wv[64];
#pragma unroll
  for (int i = 0; i < 64; i++) ids[i] = rid[i * 64 + lane];
#pragma unroll
  for (int i = 0; i < 64; i++) wv[i] = rw[i * 64 + lane];
  int cnt[NE];
#pragma unroll
  for (int e = 0; e < NE; e++) cnt[e] = 0;
#pragma unroll
  for (int i = 0; i < 64; i++){
#pragma unroll
    for (int e = 0; e < NE; e++)
      cnt[e] += __popcll(__ballot(ids[i] == e));
  }
  int offs[NE + 1]; offs[0] = 0;
#pragma unroll
  for (int e = 0; e < NE; e++) offs[e + 1] = offs[e] + cnt[e];
  if (lane == 0){
#pragma unroll
    for (int e = 0; e <= NE; e++) off[e] = offs[e];
  }
  int run[NE];
#pragma unroll
  for (int e = 0; e < NE; e++) run[e] = offs[e];
  unsigned long long ltm = (1ULL << lane) - 1ULL;
#pragma unroll
  for (int i = 0; i < 64; i++){
    int id = ids[i];
    int tok = (i * 64 + lane) >> 1;
#pragma unroll
    for (int e = 0; e < NE; e++){
      unsigned long long m = __ballot(id == e);
      if (id == e){
        int pos = run[e] + __popcll(m & ltm);
        row_tok[pos] = tok;
        row_w[pos]   = wv[i];
      }
      run[e] += __popcll(m);
    }
  }
}

// ================= FAST PATH: m97 clone — 128x128 tile, BK=64, single-buf LDS, =================
// 256 thr, acc 4x4, 3 blocks/CU. __syncthreads pacing (compiler waits); cross-block overlap
// hides the barrier drain (m97 mechanism). Swizzle: LDS[row][s] = G[row][s ^ (row&7)].

// -------- gate+up as ONE grouped GEMM over Wgu (g/u 32-col interleave), fused gelu --------
__global__ __launch_bounds__(256, 3)
void k_gu97(const __hip_bfloat16* __restrict__ Xb, const __hip_bfloat16* __restrict__ Wgu,
            const int* __restrict__ row_tok, const int* __restrict__ off,
            __hip_bfloat16* __restrict__ hbuf){
  __shared__ __align__(16) char sA[16384];   // [128 m][64 k] bf16, swizzled
  __shared__ __align__(16) char sB[16384];   // [128 n'][64 k]
  __shared__ int s_tok[128];

  const int bid = blockIdx.x;                // 1280 = e(bid&7) x 5mt x 32nt, mt inner
  const int e  = bid & 7;
  const int t  = bid >> 3;
  const int mt = t % 5;
  const int nt = t / 5;                      // 0..31 over n' (4096/128)
  const int o0 = off[e], cnt = off[e + 1] - o0;
  if (mt * 128 >= cnt) return;
  const int p0 = o0 + mt * 128;
  const int cntL = min(128, cnt - mt * 128);
  const int tid = threadIdx.x;
  const int wid = tid >> 6, lane = tid & 63;

  if (tid < 128) s_tok[tid] = row_tok[min(p0 + tid, TT*2 - 1)];
  __syncthreads();

  // staging sources: chunk = 1KB = 8 rows x 128B; lane -> row lane>>3, slot lane&7
  const int sw = (((lane & 7) ^ (lane >> 3)) & 7) << 4;     // inverse swizzle on source
  const char* asrc[4]; const char* bsrc[4];
#pragma unroll
  for (int i = 0; i < 4; i++){
    int r = (wid * 4 + i) * 8 + (lane >> 3);                // 0..127
    asrc[i] = (const char*)Xb + (size_t)s_tok[r] * 4096 + sw;
    bsrc[i] = (const char*)Wgu + ((size_t)e * 4096 + nt * 128 + r) * 4096 + sw;
  }
  const int wm = wid >> 1, wn = wid & 1;     // 2x2 waves, wave = 64m x 64n'
  const int kg = lane >> 4, ln = lane & 15;
  int aoff[4], boff[4];
#pragma unroll
  for (int f = 0; f < 4; f++){
    int m = wm * 64 + f * 16 + ln;
    aoff[f] = m * 128 + (((kg ^ (m & 7)) & 7) << 4);
    int n = wn * 64 + f * 16 + ln;
    boff[f] = n * 128 + (((kg ^ (n & 7)) & 7) << 4);
  }

  f4 acc[4][4];
#pragma unroll
  for (int a = 0; a < 4; a++)
#pragma unroll
    for (int b = 0; b < 4; b++) acc[a][b] = f4{0,0,0,0};

  for (int kt = 0; kt < 32; ++kt){
    __syncthreads();                          // prev compute done reading LDS
    const int _o = kt * 128;
#pragma unroll
    for (int i = 0; i < 4; i++) glds16(asrc[i] + _o, sA + (wid * 4 + i) * 1024);
#pragma unroll
    for (int i = 0; i < 4; i++) glds16(bsrc[i] + _o, sB + (wid * 4 + i) * 1024);
    __syncthreads();                          // compiler drains vmcnt: tile landed
#pragma unroll
    for (int ks = 0; ks < 2; ks++){
      const int kx = ks * 64;                 // slot ^= 4 -> byte ^ 0x40
      short8 af[4], bf[4];
#pragma unroll
      for (int f = 0; f < 4; f++) af[f] = *(const short8*)(sA + (aoff[f] ^ kx));
#pragma unroll
      for (int f = 0; f < 4; f++) bf[f] = *(const short8*)(sB + (boff[f] ^ kx));
#pragma unroll
      for (int fn = 0; fn < 4; fn++)
#pragma unroll
        for (int fm = 0; fm < 4; fm++)
          acc[fm][fn] = __builtin_amdgcn_mfma_f32_16x16x32_bf16(af[fm], bf[fn], acc[fm][fn], 0, 0, 0);
    }
  }
  // epilogue: fn 0,1 hold g cols, fn 2,3 hold u cols for the SAME h columns
#pragma unroll
  for (int fm = 0; fm < 4; fm++){
#pragma unroll
    for (int r = 0; r < 4; r++){
      int row = wm * 64 + fm * 16 + (lane >> 4) * 4 + r;
      if (row < cntL){
        size_t base = (size_t)(p0 + row) * ID + (size_t)nt * 64 + wn * 32 + ln;
#pragma unroll
        for (int fn = 0; fn < 2; fn++){
          float g = acc[fm][fn][r];
          float u = acc[fm][fn + 2][r];
          hbuf[base + fn * 16] = __float2bfloat16(gelu_t(g) * u);
        }
      }
    }
  }
}

// -------- down: m97 clone + weighted atomic scatter --------
__global__ __launch_bounds__(256, 3)
void k_dn97(const __hip_bfloat16* __restrict__ hbuf, const __hip_bfloat16* __restrict__ Wdt,
            const int* __restrict__ row_tok, const float* __restrict__ row_w,
            const int* __restrict__ off, float* __restrict__ out){
  __shared__ __align__(16) char sA[16384];   // [128 m][64 k]
  __shared__ __align__(16) char sB[16384];   // [128 n][64 k]
  __shared__ int s_tok[128];
  __shared__ float s_w[128];

  const int bid = blockIdx.x;                // 640 = e(bid&7) x 5mt x 16nt
  const int e  = bid & 7;
  const int t  = bid >> 3;
  const int mt = t % 5;
  const int nt = t / 5;                      // 0..15
  const int o0 = off[e], cnt = off[e + 1] - o0;
  if (mt * 128 >= cnt) return;
  const int p0 = o0 + mt * 128;
  const int cntL = min(128, cnt - mt * 128);
  const int tid = threadIdx.x;
  const int wid = tid >> 6, lane = tid & 63;

  if (tid < 128){
    int p = min(p0 + tid, TT*2 - 1);
    s_tok[tid] = row_tok[p];
    s_w[tid]   = row_w[p];
  }
  __syncthreads();

  const int sw = (((lane & 7) ^ (lane >> 3)) & 7) << 4;
  const char* asrc[4]; const char* bsrc[4];
#pragma unroll
  for (int i = 0; i < 4; i++){
    int r = (wid * 4 + i) * 8 + (lane >> 3);
    int p = min(p0 + r, TT*2 - 1);
    asrc[i] = (const char*)hbuf + (size_t)p * 4096 + sw;
    bsrc[i] = (const char*)Wdt + ((size_t)e * 2048 + nt * 128 + r) * 4096 + sw;
  }
  const int wm = wid >> 1, wn = wid & 1;
  const int kg = lane >> 4, ln = lane & 15;
  int aoff[4], boff[4];
#pragma unroll
  for (int f = 0; f < 4; f++){
    int m = wm * 64 + f * 16 + ln;
    aoff[f] = m * 128 + (((kg ^ (m & 7)) & 7) << 4);
    int n = wn * 64 + f * 16 + ln;
    boff[f] = n * 128 + (((kg ^ (n & 7)) & 7) << 4);
  }

  f4 acc[4][4];
#pragma unroll
  for (int a = 0; a < 4; a++)
#pragma unroll
    for (int b = 0; b < 4; b++) acc[a][b] = f4{0,0,0,0};

  for (int kt = 0; kt < 32; ++kt){
    __syncthreads();
    const int _o = kt * 128;
#pragma unroll
    for (int i = 0; i < 4; i++) glds16(asrc[i] + _o, sA + (wid * 4 + i) * 1024);
#pragma unroll
    for (int i = 0; i < 4; i++) glds16(bsrc[i] + _o, sB + (wid * 4 + i) * 1024);
    __syncthreads();
#pragma unroll
    for (int ks = 0; ks < 2; ks++){
      const int kx = ks * 64;
      short8 af[4], bf[4];
#pragma unroll
      for (int f = 0; f < 4; f++) af[f] = *(const short8*)(sA + (aoff[f] ^ kx));
#pragma unroll
      for (int f = 0; f < 4; f++) bf[f] = *(const short8*)(sB + (boff[f] ^ kx));
#pragma unroll
      for (int fn = 0; fn < 4; fn++)
#pragma unroll
        for (int fm = 0; fm < 4; fm++)
          acc[fm][fn] = __builtin_amdgcn_mfma_f32_16x16x32_bf16(af[fm], bf[fn], acc[fm][fn], 0, 0, 0);
    }
  }
#pragma unroll
  for (int fm = 0; fm < 4; fm++){
#pragma unroll
    for (int r = 0; r < 4; r++){
      int row = wm * 64 + fm * 16 + (lane >> 4) * 4 + r;
      if (row < cntL){
        int tok = s_tok[row];
        float w = s_w[row];
        float* ob = out + (size_t)tok * HD + (size_t)nt * 128 + wn * 64 + ln;
#pragma unroll
        for (int fn = 0; fn < 4; fn++)
          atomicAdd(ob + fn * 16, acc[fm][fn][r] * w);
      }
    }
  }
}

// ================= FALLBACK PATH (round-3 kernels, known-good) =================

__global__ __launch_bounds__(256, 3)
void k_gateup_r3(const __hip_bfloat16* __restrict__ Xb, const float* __restrict__ Wg,
                 const float* __restrict__ Wu, const int* __restrict__ row_tok,
                 const int* __restrict__ off, __hip_bfloat16* __restrict__ hbuf){
  __shared__ __align__(16) char sA[2][16384];
  __shared__ __align__(16) char sBg[8192];
  __shared__ __align__(16) char sBu[8192];
  __shared__ int s_tok[128];

  const int bid = blockIdx.x;
  const int e  = bid & 7;
  const int mt = (bid >> 3) & 7;
  const int nt = bid >> 6;
  const int o0 = off[e], cnt = off[e + 1] - o0;
  if (mt * 128 >= cnt) return;
  const int p0 = o0 + mt * 128;
  const int cntL = min(128, cnt - mt * 128);
  const int tid = threadIdx.x;
  const int wid = tid >> 6, lane = tid & 63;

  if (tid < 128) s_tok[tid] = row_tok[min(p0 + tid, TT*2 - 1)];
  __syncthreads();

  const char* asrc[4];
#pragma unroll
  for (int i = 0; i < 4; i++){
    int c = wid * 4 + i;
    int r = c * 8 + (lane >> 3);
    asrc[i] = (const char*)Xb + (size_t)s_tok[r] * (HD * 2)
            + ((((lane & 7) ^ (lane >> 3)) & 7) << 4);
  }
  const int n0 = (tid & 15) * 4;
  const int k0 = (tid >> 4) * 4;
  const size_t wb = (size_t)e * HD * ID + (size_t)k0 * ID + (size_t)nt * 64 + n0;
  const float* gsrc = Wg + wb;
  const float* usrc = Wu + wb;
  int bw[4];
#pragma unroll
  for (int j = 0; j < 4; j++)
    bw[j] = (n0 + j) * 128 + ((((k0 >> 3) ^ (tid & 7) ^ (j << 1)) & 7) << 4) + ((k0 & 4) << 1);

  const int wm = wid >> 1, wn = wid & 1;
  const int kg = lane >> 4, ln = lane & 15;
  int aoff[2][4], boff[2][2];
#pragma unroll
  for (int ks = 0; ks < 2; ks++){
    int qs = ks * 4 + kg;
#pragma unroll
    for (int f = 0; f < 4; f++){
      int m = wm * 64 + f * 16 + ln;
      aoff[ks][f] = m * 128 + (((qs ^ (ln & 7)) & 7) << 4);
    }
#pragma unroll
    for (int f = 0; f < 2; f++){
      int n = wn * 32 + f * 16 + ln;
      boff[ks][f] = n * 128 + (((qs ^ swzB(n)) & 7) << 4);
    }
  }

  f4 accg[4][2], accu[4][2];
#pragma unroll
  for (int a = 0; a < 4; a++)
#pragma unroll
    for (int b = 0; b < 2; b++){ accg[a][b] = f4{0,0,0,0}; accu[a][b] = f4{0,0,0,0}; }

#pragma unroll
  for (int i = 0; i < 4; i++) glds16(asrc[i], &sA[0][(wid * 4 + i) * 1024]);
  f4 g0, g1, g2, g3, u0, u1, u2, u3;
  { const f4* p = (const f4*)gsrc; g0 = p[0]; g1 = p[ID/4]; g2 = p[ID/2]; g3 = p[3*ID/4];
    const f4* q = (const f4*)usrc; u0 = q[0]; u1 = q[ID/4]; u2 = q[ID/2]; u3 = q[3*ID/4]; }

  for (int kt = 0; kt < 32; ++kt){
    softbar();
    if (kt + 1 < 32){
      char* dst = &sA[(kt + 1) & 1][0] + (wid * 4) * 1024;
#pragma unroll
      for (int i = 0; i < 4; i++) glds16(asrc[i] + (size_t)(kt + 1) * 128, dst + i * 1024);
    }
#pragma unroll
    for (int j = 0; j < 4; j++){
      *(uint2*)(sBg + bw[j]) = uint2{ pk2(g0[j], g1[j]), pk2(g2[j], g3[j]) };
      *(uint2*)(sBu + bw[j]) = uint2{ pk2(u0[j], u1[j]), pk2(u2[j], u3[j]) };
    }
    softbar();
    if (kt + 1 < 32){
      const f4* p = (const f4*)(gsrc + (size_t)(kt + 1) * 64 * ID);
      g0 = p[0]; g1 = p[ID/4]; g2 = p[ID/2]; g3 = p[3*ID/4];
      const f4* q = (const f4*)(usrc + (size_t)(kt + 1) * 64 * ID);
      u0 = q[0]; u1 = q[ID/4]; u2 = q[ID/2]; u3 = q[3*ID/4];
    }
    const char* A = &sA[kt & 1][0];
#pragma unroll
    for (int ks = 0; ks < 2; ks++){
      short8 af[4];
#pragma unroll
      for (int f = 0; f < 4; f++) af[f] = *(const short8*)(A + aoff[ks][f]);
#pragma unroll
      for (int fn = 0; fn < 2; fn++){
        short8 bg = *(const short8*)(sBg + boff[ks][fn]);
        short8 bu = *(const short8*)(sBu + boff[ks][fn]);
#pragma unroll
        for (int fm = 0; fm < 4; fm++){
          accg[fm][fn] = __builtin_amdgcn_mfma_f32_16x16x32_bf16(af[fm], bg, accg[fm][fn], 0, 0, 0);
          accu[fm][fn] = __builtin_amdgcn_mfma_f32_16x16x32_bf16(af[fm], bu, accu[fm][fn], 0, 0, 0);
        }
      }
    }
  }
#pragma unroll
  for (int fm = 0; fm < 4; fm++){
#pragma unroll
    for (int r = 0; r < 4; r++){
      int row = wm * 64 + fm * 16 + (lane >> 4) * 4 + r;
      if (row < cntL){
        size_t base = (size_t)(p0 + row) * ID + (size_t)nt * 64 + wn * 32 + ln;
#pragma unroll
        for (int fn = 0; fn < 2; fn++){
          float g = accg[fm][fn][r];
          float u = accu[fm][fn][r];
          hbuf[base + fn * 16] = __float2bfloat16(gelu_t(g) * u);
        }
      }
    }
  }
}

__global__ __launch_bounds__(256, 3)
void k_down_r3(const __hip_bfloat16* __restrict__ hbuf, const float* __restrict__ Wd,
               const int* __restrict__ row_tok, const float* __restrict__ row_w,
               const int* __restrict__ off, float* __restrict__ out){
  __shared__ __align__(16) char sA[2][16384];
  __shared__ __align__(16) char sB[16384];
  __shared__ int s_tok[128];
  __shared__ float s_w[128];

  const int bid = blockIdx.x;
  const int e  = bid & 7;
  const int mt = (bid >> 3) & 7;
  const int nt = bid >> 6;
  const int o0 = off[e], cnt = off[e + 1] - o0;
  if (mt * 128 >= cnt) return;
  const int p0 = o0 + mt * 128;
  const int cntL = min(128, cnt - mt * 128);
  const int tid = threadIdx.x;
  const int wid = tid >> 6, lane = tid & 63;

  if (tid < 128){
    int p = min(p0 + tid, TT*2 - 1);
    s_tok[tid] = row_tok[p];
    s_w[tid]   = row_w[p];
  }
  __syncthreads();

  const char* asrc[4];
#pragma unroll
  for (int i = 0; i < 4; i++){
    int c = wid * 4 + i;
    int r = c * 8 + (lane >> 3);
    int p = min(p0 + r, TT*2 - 1);
    asrc[i] = (const char*)hbuf + (size_t)p * (ID * 2)
            + ((((lane & 7) ^ (lane >> 3)) & 7) << 4);
  }
  const int n0 = (tid & 31) * 4;
  const int k0 = (tid >> 5) * 8;
  const float* bsrc = Wd + (size_t)e * ID * HD + (size_t)k0 * HD + (size_t)nt * 128 + n0;
  int bw[4];
#pragma unroll
  for (int j = 0; j < 4; j++)
    bw[j] = (n0 + j) * 128 + ((((k0 >> 3) ^ (tid & 7) ^ (j << 1)) & 7) << 4);

  const int wm = wid >> 1, wn = wid & 1;
  const int kg = lane >> 4, ln = lane & 15;
  int aoff[2][4], boff[2][4];
#pragma unroll
  for (int ks = 0; ks < 2; ks++){
    int qs = ks * 4 + kg;
#pragma unroll
    for (int f = 0; f < 4; f++){
      int m = wm * 64 + f * 16 + ln;
      aoff[ks][f] = m * 128 + (((qs ^ (ln & 7)) & 7) << 4);
      int n = wn * 64 + f * 16 + ln;
      boff[ks][f] = n * 128 + (((qs ^ swzB(n)) & 7) << 4);
    }
  }

  f4 acc[4][4];
#pragma unroll
  for (int a = 0; a < 4; a++)
#pragma unroll
    for (int b = 0; b < 4; b++) acc[a][b] = f4{0,0,0,0};

#pragma unroll
  for (int i = 0; i < 4; i++) glds16(asrc[i], &sA[0][(wid * 4 + i) * 1024]);
  f4 r0, r1, r2, r3, r4, r5, r6, r7;
  { const f4* p = (const f4*)bsrc;
    r0 = p[0]; r1 = p[HD/4]; r2 = p[HD/2]; r3 = p[3*HD/4];
    r4 = p[HD]; r5 = p[5*HD/4]; r6 = p[3*HD/2]; r7 = p[7*HD/4]; }

  for (int kt = 0; kt < 32; ++kt){
    softbar();
    if (kt + 1 < 32){
      char* dst = &sA[(kt + 1) & 1][0] + (wid * 4) * 1024;
#pragma unroll
      for (int i = 0; i < 4; i++) glds16(asrc[i] + (size_t)(kt + 1) * 128, dst + i * 1024);
    }
#pragma unroll
    for (int j = 0; j < 4; j++){
      *(uint4*)(sB + bw[j]) = uint4{ pk2(r0[j], r1[j]), pk2(r2[j], r3[j]),
                                     pk2(r4[j], r5[j]), pk2(r6[j], r7[j]) };
    }
    softbar();
    if (kt + 1 < 32){
      const f4* p = (const f4*)(bsrc + (size_t)(kt + 1) * 64 * HD);
      r0 = p[0]; r1 = p[HD/4]; r2 = p[HD/2]; r3 = p[3*HD/4];
      r4 = p[HD]; r5 = p[5*HD/4]; r6 = p[3*HD/2]; r7 = p[7*HD/4];
    }
    const char* A = &sA[kt & 1][0];
#pragma unroll
    for (int ks = 0; ks < 2; ks++){
      short8 af[4];
#pragma unroll
      for (int f = 0; f < 4; f++) af[f] = *(const short8*)(A + aoff[ks][f]);
#pragma unroll
      for (int fn = 0; fn < 4; fn++){
        short8 bf = *(const short8*)(sB + boff[ks][fn]);
#pragma unroll
        for (int fm = 0; fm < 4; fm++)
          acc[fm][fn] = __builtin_amdgcn_mfma_f32_16x16x32_bf16(af[fm], bf, acc[fm][fn], 0, 0, 0);
      }
    }
  }
#pragma unroll
  for (int fm = 0; fm < 4; fm++){
#pragma unroll
    for (int r = 0; r < 4; r++){
      int row = wm * 64 + fm * 16 + (lane >> 4) * 4 + r;
      if (row < cntL){
        int tok = s_tok[row];
        float w = s_w[row];
        float* ob = out + (size_t)tok * HD + (size_t)nt * 128 + wn * 64 + ln;
#pragma unroll
        for (int fn = 0; fn < 4; fn++)
          atomicAdd(ob + fn * 16, acc[fm][fn][r] * w);
      }
    }
  }
}

extern "C" void kernel_launch(void* const* d_in, const int* in_sizes, int n_in,
                              void* d_out, int out_size, void* d_ws, size_t ws_size,
                              hipStream_t stream){
  (void)in_sizes; (void)n_in; (void)out_size;
  const float* X  = (const float*)d_in[0];
  const float* RL = (const float*)d_in[1];
  const float* SC = (const float*)d_in[2];
  const float* Wg = (const float*)d_in[3];
  const float* Wu = (const float*)d_in[4];
  const float* Wd = (const float*)d_in[5];
  float* out = (float*)d_out;

  char* ws = (char*)d_ws;
  int*   rid     = (int*)(ws);
  float* rw      = (float*)(ws + 16384);
  int*   row_tok = (int*)(ws + 32768);
  float* row_w   = (float*)(ws + 49152);
  int*   off     = (int*)(ws + 65536);
  __hip_bfloat16* hbuf = (__hip_bfloat16*)(ws + 66560);                      // 16 MiB
  __hip_bfloat16* Xb   = (__hip_bfloat16*)(ws + 66560 + 16777216ull);        // 8 MiB
  __hip_bfloat16* Wb   = (__hip_bfloat16*)(ws + 66560 + 16777216ull + 8388608ull);
  const size_t WME = (size_t)NE * 2048 * 2048;                               // elems per tensor
  const size_t GU  = 2 * WME;                                                // gu region elems
  const size_t need = 66560ull + 16777216ull + 8388608ull + 3ull * WME * 2ull;

  hipMemsetAsync(d_out, 0, (size_t)TT * HD * sizeof(float), stream);
  k_cvtx <<<2048, 256, 0, stream>>>(X, Xb);
  k_route<<<TT / 256, 256, 0, stream>>>(RL, SC, rid, rw);
  k_lists<<<1, 64, 0, stream>>>(rid, rw, row_tok, row_w, off);

  if (ws_size >= need){
    k_cvtw<<<12288, 256, 0, stream>>>(Wg, Wu, Wd, Wb);
    k_gu97<<<1280, 256, 0, stream>>>(Xb, Wb, row_tok, off, hbuf);
    k_dn97<<< 640, 256, 0, stream>>>(hbuf, Wb + GU, row_tok, row_w, off, out);
  } else {
    k_gateup_r3<<<2048, 256, 0, stream>>>(Xb, Wg, Wu, row_tok, off, hbuf);
    k_down_r3  <<<1024, 256, 0, stream>>>(hbuf, Wd, row_tok, row_w, off, out);
  }
}

// Round 12
// 353.815 us; speedup vs baseline: 1.3399x; 1.0163x over previous
//
#include <hip/hip_runtime.h>
#include <hip/hip_bf16.h>

#define TT 2048
#define HD 2048
#define ID 2048
#define NE 8

typedef __attribute__((ext_vector_type(8))) short short8;
typedef __attribute__((ext_vector_type(4))) float f4;

__device__ __forceinline__ unsigned short b16(float f){
  union { __hip_bfloat16 b; unsigned short u; } x;
  x.b = __float2bfloat16(f);
  return x.u;
}
__device__ __forceinline__ unsigned pk2(float lo, float hi){
  return (unsigned)b16(lo) | ((unsigned)b16(hi) << 16);
}
__device__ __forceinline__ float gelu_t(float x){
  float y = 0.7978845608028654f * (x + 0.044715f * x * x * x);
  float t = 1.0f - 2.0f / (__expf(2.0f * y) + 1.0f);
  return 0.5f * x * (1.0f + t);
}
__device__ __forceinline__ void glds16(const void* g, void* l){
  __builtin_amdgcn_global_load_lds(
      (const __attribute__((address_space(1))) unsigned*)g,
      (__attribute__((address_space(3))) unsigned*)l, 16, 0, 0);
}
__device__ __forceinline__ void softbar(){
  asm volatile("s_waitcnt lgkmcnt(0)" ::: "memory");
  __builtin_amdgcn_s_barrier();
  __builtin_amdgcn_sched_barrier(0);
}
__device__ __forceinline__ int swzB(int n){ return (((n >> 2) & 7) ^ ((n & 3) << 1)) & 7; }

// ---------------- X fp32 -> bf16 ----------------
__global__ void k_cvtx(const float* __restrict__ X, __hip_bfloat16* __restrict__ Xb){
  int i = blockIdx.x * 256 + threadIdx.x;
  const f4* src = (const f4*)X + (size_t)i * 2;
  f4 a = src[0], b = src[1];
  uint4 o = { pk2(a[0],a[1]), pk2(a[2],a[3]), pk2(b[0],b[1]), pk2(b[2],b[3]) };
  ((uint4*)Xb)[i] = o;
}

// -------- W fp32 [e][k][n] -> bf16 transposed layouts (conflict-free rotation transpose) ----
// m=0 (gate), m=1 (up): Wgu[e][n'][k], n' = (n>>5)*64 + (n&31) + m*32  (32-col g/u interleave)
// m=2 (down):           Wdt[e][n][k]
// 64k x 64n tile; LDS layout: s_t[k][ (n + 4k + 16*(k>>4)) & 63 ]
//  - phase-1: ds_write_b128, 2..4-way (hidden under global latency)
//  - phase-2: scalar u32 reads, bank = (n + 4i + 16kq)&31 -> uniform 2-way (free)
//  - output: 2x uint4 per thread; 4-lane group covers 128B contiguous
__global__ __launch_bounds__(256)
void k_cvtw(const float* __restrict__ Wg, const float* __restrict__ Wu,
            const float* __restrict__ Wd, __hip_bfloat16* __restrict__ Wb){
  __shared__ float s_t[64 * 64];
  const int bid = blockIdx.x;                 // 3m x 8e x 32kt x 32nt = 24576
  const int nt = bid & 31;
  const int kt = (bid >> 5) & 31;
  const int e  = (bid >> 10) & 7;
  const int m  = bid >> 13;
  const float* S = (m == 0 ? Wg : (m == 1 ? Wu : Wd))
                 + (size_t)e * HD * ID + (size_t)(kt * 64) * 2048 + nt * 64;
  const int tid = threadIdx.x;
  {
    const int k = tid >> 2;
    const int r = 4 * k + 16 * (k >> 4);
    const float* src = S + (size_t)k * 2048;
#pragma unroll
    for (int j = 0; j < 4; j++){
      int n = (tid & 3) * 4 + 16 * j;
      f4 v = *(const f4*)(src + n);
      *(f4*)(s_t + k * 64 + ((n + r) & 63)) = v;
    }
  }
  __syncthreads();
  const int n = tid >> 2, kq = tid & 3;
  float v[16];
#pragma unroll
  for (int i = 0; i < 16; i++){
    int k = kq * 16 + i;
    v[i] = s_t[k * 64 + ((n + 4 * k + 16 * kq) & 63)];
  }
  unsigned o[8];
#pragma unroll
  for (int j = 0; j < 8; j++) o[j] = pk2(v[2*j], v[2*j+1]);
  size_t drow;
  if (m < 2){
    int ng = nt * 64 + n;
    drow = (size_t)e * 4096 + (ng >> 5) * 64 + (ng & 31) + m * 32;   // gu region
  } else {
    drow = (size_t)8 * 4096 + (size_t)e * 2048 + nt * 64 + n;        // d region
  }
  char* dp = (char*)Wb + drow * 4096 + (size_t)kt * 128 + kq * 32;
  *(uint4*)dp        = uint4{ o[0], o[1], o[2], o[3] };
  *(uint4*)(dp + 16) = uint4{ o[4], o[5], o[6], o[7] };
}

// ---------------- routing ----------------
__global__ void k_route(const float* __restrict__ lg, const float* __restrict__ sc,
                        int* __restrict__ rid, float* __restrict__ rw){
  int t = blockIdx.x * blockDim.x + threadIdx.x;
  if (t >= TT) return;
  float l[NE];
#pragma unroll
  for (int e = 0; e < NE; e++) l[e] = lg[t * NE + e];
  float mx = l[0];
#pragma unroll
  for (int e = 1; e < NE; e++) mx = fmaxf(mx, l[e]);
  float p[NE];
#pragma unroll
  for (int e = 0; e < NE; e++) p[e] = __expf(l[e] - mx);
  int i0 = 0; float b0 = l[0];
#pragma unroll
  for (int e = 1; e < NE; e++) if (l[e] > b0){ b0 = l[e]; i0 = e; }
  int i1 = -1; float b1 = -1e30f;
#pragma unroll
  for (int e = 0; e < NE; e++) if (e != i0 && l[e] > b1){ b1 = l[e]; i1 = e; }
  float p0 = p[i0], p1 = p[i1];
  float rn = p0 + p1; rn = (rn > 0.f) ? rn : 1.f;
  rw[t*2]   = p0 / rn * sc[i0];
  rw[t*2+1] = p1 / rn * sc[i1];
  rid[t*2]  = i0;
  rid[t*2+1]= i1;
}

// ---------------- deterministic per-expert compaction ----------------
__global__ void k_lists(const int* __restrict__ rid, const float* __restrict__ rw,
                        int* __restrict__ row_tok, float* __restrict__ row_w,
                        int* __restrict__ off){
  int lane = threadIdx.x;            // 64 threads
  int ids[64]; float wv[64];
#pragma unroll
  for (int i = 0; i < 64; i++) ids[i] = rid[i * 64 + lane];
#pragma unroll
  for (int i = 0; i < 64; i++) wv[i] = rw[i * 64 + lane];
  int cnt[NE];
#pragma unroll
  for (int e = 0; e < NE; e++) cnt[e] = 0;
#pragma unroll
  for (int i = 0; i < 64; i++){
#pragma unroll
    for (int e = 0; e < NE; e++)
      cnt[e] += __popcll(__ballot(ids[i] == e));
  }
  int offs[NE + 1]; offs[0] = 0;
#pragma unroll
  for (int e = 0; e < NE; e++) offs[e + 1] = offs[e] + cnt[e];
  if (lane == 0){
#pragma unroll
    for (int e = 0; e <= NE; e++) off[e] = offs[e];
  }
  int run[NE];
#pragma unroll
  for (int e = 0; e < NE; e++) run[e] = offs[e];
  unsigned long long ltm = (1ULL << lane) - 1ULL;
#pragma unroll
  for (int i = 0; i < 64; i++){
    int id = ids[i];
    int tok = (i * 64 + lane) >> 1;
#pragma unroll
    for (int e = 0; e < NE; e++){
      unsigned long long m = __ballot(id == e);
      if (id == e){
        int pos = run[e] + __popcll(m & ltm);
        row_tok[pos] = tok;
        row_w[pos]   = wv[i];
      }
      run[e] += __popcll(m);
    }
  }
}

// ================= FAST PATH: m97 clone — 128x128 tile, BK=64, single-buf LDS, =================
// 256 thr, acc 4x4, 3 blocks/CU. __syncthreads pacing (compiler waits); cross-block overlap
// hides the barrier drain (m97 mechanism). Swizzle: LDS[row][s] = G[row][s ^ (row&7)].

// -------- gate+up as ONE grouped GEMM over Wgu (g/u 32-col interleave), fused gelu --------
__global__ __launch_bounds__(256, 3)
void k_gu97(const __hip_bfloat16* __restrict__ Xb, const __hip_bfloat16* __restrict__ Wgu,
            const int* __restrict__ row_tok, const int* __restrict__ off,
            __hip_bfloat16* __restrict__ hbuf){
  __shared__ __align__(16) char sA[16384];   // [128 m][64 k] bf16, swizzled
  __shared__ __align__(16) char sB[16384];   // [128 n'][64 k]
  __shared__ int s_tok[128];

  const int bid = blockIdx.x;                // 1280 = e(bid&7) x 5mt x 32nt, mt inner
  const int e  = bid & 7;
  const int t  = bid >> 3;
  const int mt = t % 5;
  const int nt = t / 5;                      // 0..31 over n' (4096/128)
  const int o0 = off[e], cnt = off[e + 1] - o0;
  if (mt * 128 >= cnt) return;
  const int p0 = o0 + mt * 128;
  const int cntL = min(128, cnt - mt * 128);
  const int tid = threadIdx.x;
  const int wid = tid >> 6, lane = tid & 63;

  if (tid < 128) s_tok[tid] = row_tok[min(p0 + tid, TT*2 - 1)];
  __syncthreads();

  // staging sources: chunk = 1KB = 8 rows x 128B; lane -> row lane>>3, slot lane&7
  const int sw = (((lane & 7) ^ (lane >> 3)) & 7) << 4;     // inverse swizzle on source
  const char* asrc[4]; const char* bsrc[4];
#pragma unroll
  for (int i = 0; i < 4; i++){
    int r = (wid * 4 + i) * 8 + (lane >> 3);                // 0..127
    asrc[i] = (const char*)Xb + (size_t)s_tok[r] * 4096 + sw;
    bsrc[i] = (const char*)Wgu + ((size_t)e * 4096 + nt * 128 + r) * 4096 + sw;
  }
  const int wm = wid >> 1, wn = wid & 1;     // 2x2 waves, wave = 64m x 64n'
  const int kg = lane >> 4, ln = lane & 15;
  int aoff[4], boff[4];
#pragma unroll
  for (int f = 0; f < 4; f++){
    int m = wm * 64 + f * 16 + ln;
    aoff[f] = m * 128 + (((kg ^ (m & 7)) & 7) << 4);
    int n = wn * 64 + f * 16 + ln;
    boff[f] = n * 128 + (((kg ^ (n & 7)) & 7) << 4);
  }

  f4 acc[4][4];
#pragma unroll
  for (int a = 0; a < 4; a++)
#pragma unroll
    for (int b = 0; b < 4; b++) acc[a][b] = f4{0,0,0,0};

  for (int kt = 0; kt < 32; ++kt){
    __syncthreads();                          // prev compute done reading LDS
    const int _o = kt * 128;
#pragma unroll
    for (int i = 0; i < 4; i++) glds16(asrc[i] + _o, sA + (wid * 4 + i) * 1024);
#pragma unroll
    for (int i = 0; i < 4; i++) glds16(bsrc[i] + _o, sB + (wid * 4 + i) * 1024);
    __syncthreads();                          // compiler drains vmcnt: tile landed
#pragma unroll
    for (int ks = 0; ks < 2; ks++){
      const int kx = ks * 64;                 // slot ^= 4 -> byte ^ 0x40
      short8 af[4], bf[4];
#pragma unroll
      for (int f = 0; f < 4; f++) af[f] = *(const short8*)(sA + (aoff[f] ^ kx));
#pragma unroll
      for (int f = 0; f < 4; f++) bf[f] = *(const short8*)(sB + (boff[f] ^ kx));
#pragma unroll
      for (int fn = 0; fn < 4; fn++)
#pragma unroll
        for (int fm = 0; fm < 4; fm++)
          acc[fm][fn] = __builtin_amdgcn_mfma_f32_16x16x32_bf16(af[fm], bf[fn], acc[fm][fn], 0, 0, 0);
    }
  }
  // epilogue: fn 0,1 hold g cols, fn 2,3 hold u cols for the SAME h columns
#pragma unroll
  for (int fm = 0; fm < 4; fm++){
#pragma unroll
    for (int r = 0; r < 4; r++){
      int row = wm * 64 + fm * 16 + (lane >> 4) * 4 + r;
      if (row < cntL){
        size_t base = (size_t)(p0 + row) * ID + (size_t)nt * 64 + wn * 32 + ln;
#pragma unroll
        for (int fn = 0; fn < 2; fn++){
          float g = acc[fm][fn][r];
          float u = acc[fm][fn + 2][r];
          hbuf[base + fn * 16] = __float2bfloat16(gelu_t(g) * u);
        }
      }
    }
  }
}

// -------- down: m97 clone + weighted atomic scatter --------
__global__ __launch_bounds__(256, 3)
void k_dn97(const __hip_bfloat16* __restrict__ hbuf, const __hip_bfloat16* __restrict__ Wdt,
            const int* __restrict__ row_tok, const float* __restrict__ row_w,
            const int* __restrict__ off, float* __restrict__ out){
  __shared__ __align__(16) char sA[16384];   // [128 m][64 k]
  __shared__ __align__(16) char sB[16384];   // [128 n][64 k]
  __shared__ int s_tok[128];
  __shared__ float s_w[128];

  const int bid = blockIdx.x;                // 640 = e(bid&7) x 5mt x 16nt
  const int e  = bid & 7;
  const int t  = bid >> 3;
  const int mt = t % 5;
  const int nt = t / 5;                      // 0..15
  const int o0 = off[e], cnt = off[e + 1] - o0;
  if (mt * 128 >= cnt) return;
  const int p0 = o0 + mt * 128;
  const int cntL = min(128, cnt - mt * 128);
  const int tid = threadIdx.x;
  const int wid = tid >> 6, lane = tid & 63;

  if (tid < 128){
    int p = min(p0 + tid, TT*2 - 1);
    s_tok[tid] = row_tok[p];
    s_w[tid]   = row_w[p];
  }
  __syncthreads();

  const int sw = (((lane & 7) ^ (lane >> 3)) & 7) << 4;
  const char* asrc[4]; const char* bsrc[4];
#pragma unroll
  for (int i = 0; i < 4; i++){
    int r = (wid * 4 + i) * 8 + (lane >> 3);
    int p = min(p0 + r, TT*2 - 1);
    asrc[i] = (const char*)hbuf + (size_t)p * 4096 + sw;
    bsrc[i] = (const char*)Wdt + ((size_t)e * 2048 + nt * 128 + r) * 4096 + sw;
  }
  const int wm = wid >> 1, wn = wid & 1;
  const int kg = lane >> 4, ln = lane & 15;
  int aoff[4], boff[4];
#pragma unroll
  for (int f = 0; f < 4; f++){
    int m = wm * 64 + f * 16 + ln;
    aoff[f] = m * 128 + (((kg ^ (m & 7)) & 7) << 4);
    int n = wn * 64 + f * 16 + ln;
    boff[f] = n * 128 + (((kg ^ (n & 7)) & 7) << 4);
  }

  f4 acc[4][4];
#pragma unroll
  for (int a = 0; a < 4; a++)
#pragma unroll
    for (int b = 0; b < 4; b++) acc[a][b] = f4{0,0,0,0};

  for (int kt = 0; kt < 32; ++kt){
    __syncthreads();
    const int _o = kt * 128;
#pragma unroll
    for (int i = 0; i < 4; i++) glds16(asrc[i] + _o, sA + (wid * 4 + i) * 1024);
#pragma unroll
    for (int i = 0; i < 4; i++) glds16(bsrc[i] + _o, sB + (wid * 4 + i) * 1024);
    __syncthreads();
#pragma unroll
    for (int ks = 0; ks < 2; ks++){
      const int kx = ks * 64;
      short8 af[4], bf[4];
#pragma unroll
      for (int f = 0; f < 4; f++) af[f] = *(const short8*)(sA + (aoff[f] ^ kx));
#pragma unroll
      for (int f = 0; f < 4; f++) bf[f] = *(const short8*)(sB + (boff[f] ^ kx));
#pragma unroll
      for (int fn = 0; fn < 4; fn++)
#pragma unroll
        for (int fm = 0; fm < 4; fm++)
          acc[fm][fn] = __builtin_amdgcn_mfma_f32_16x16x32_bf16(af[fm], bf[fn], acc[fm][fn], 0, 0, 0);
    }
  }
#pragma unroll
  for (int fm = 0; fm < 4; fm++){
#pragma unroll
    for (int r = 0; r < 4; r++){
      int row = wm * 64 + fm * 16 + (lane >> 4) * 4 + r;
      if (row < cntL){
        int tok = s_tok[row];
        float w = s_w[row];
        float* ob = out + (size_t)tok * HD + (size_t)nt * 128 + wn * 64 + ln;
#pragma unroll
        for (int fn = 0; fn < 4; fn++)
          atomicAdd(ob + fn * 16, acc[fm][fn][r] * w);
      }
    }
  }
}

// ================= FALLBACK PATH (round-3 kernels, known-good) =================

__global__ __launch_bounds__(256, 3)
void k_gateup_r3(const __hip_bfloat16* __restrict__ Xb, const float* __restrict__ Wg,
                 const float* __restrict__ Wu, const int* __restrict__ row_tok,
                 const int* __restrict__ off, __hip_bfloat16* __restrict__ hbuf){
  __shared__ __align__(16) char sA[2][16384];
  __shared__ __align__(16) char sBg[8192];
  __shared__ __align__(16) char sBu[8192];
  __shared__ int s_tok[128];

  const int bid = blockIdx.x;
  const int e  = bid & 7;
  const int mt = (bid >> 3) & 7;
  const int nt = bid >> 6;
  const int o0 = off[e], cnt = off[e + 1] - o0;
  if (mt * 128 >= cnt) return;
  const int p0 = o0 + mt * 128;
  const int cntL = min(128, cnt - mt * 128);
  const int tid = threadIdx.x;
  const int wid = tid >> 6, lane = tid & 63;

  if (tid < 128) s_tok[tid] = row_tok[min(p0 + tid, TT*2 - 1)];
  __syncthreads();

  const char* asrc[4];
#pragma unroll
  for (int i = 0; i < 4; i++){
    int c = wid * 4 + i;
    int r = c * 8 + (lane >> 3);
    asrc[i] = (const char*)Xb + (size_t)s_tok[r] * (HD * 2)
            + ((((lane & 7) ^ (lane >> 3)) & 7) << 4);
  }
  const int n0 = (tid & 15) * 4;
  const int k0 = (tid >> 4) * 4;
  const size_t wb = (size_t)e * HD * ID + (size_t)k0 * ID + (size_t)nt * 64 + n0;
  const float* gsrc = Wg + wb;
  const float* usrc = Wu + wb;
  int bw[4];
#pragma unroll
  for (int j = 0; j < 4; j++)
    bw[j] = (n0 + j) * 128 + ((((k0 >> 3) ^ (tid & 7) ^ (j << 1)) & 7) << 4) + ((k0 & 4) << 1);

  const int wm = wid >> 1, wn = wid & 1;
  const int kg = lane >> 4, ln = lane & 15;
  int aoff[2][4], boff[2][2];
#pragma unroll
  for (int ks = 0; ks < 2; ks++){
    int qs = ks * 4 + kg;
#pragma unroll
    for (int f = 0; f < 4; f++){
      int m = wm * 64 + f * 16 + ln;
      aoff[ks][f] = m * 128 + (((qs ^ (ln & 7)) & 7) << 4);
    }
#pragma unroll
    for (int f = 0; f < 2; f++){
      int n = wn * 32 + f * 16 + ln;
      boff[ks][f] = n * 128 + (((qs ^ swzB(n)) & 7) << 4);
    }
  }

  f4 accg[4][2], accu[4][2];
#pragma unroll
  for (int a = 0; a < 4; a++)
#pragma unroll
    for (int b = 0; b < 2; b++){ accg[a][b] = f4{0,0,0,0}; accu[a][b] = f4{0,0,0,0}; }

#pragma unroll
  for (int i = 0; i < 4; i++) glds16(asrc[i], &sA[0][(wid * 4 + i) * 1024]);
  f4 g0, g1, g2, g3, u0, u1, u2, u3;
  { const f4* p = (const f4*)gsrc; g0 = p[0]; g1 = p[ID/4]; g2 = p[ID/2]; g3 = p[3*ID/4];
    const f4* q = (const f4*)usrc; u0 = q[0]; u1 = q[ID/4]; u2 = q[ID/2]; u3 = q[3*ID/4]; }

  for (int kt = 0; kt < 32; ++kt){
    softbar();
    if (kt + 1 < 32){
      char* dst = &sA[(kt + 1) & 1][0] + (wid * 4) * 1024;
#pragma unroll
      for (int i = 0; i < 4; i++) glds16(asrc[i] + (size_t)(kt + 1) * 128, dst + i * 1024);
    }
#pragma unroll
    for (int j = 0; j < 4; j++){
      *(uint2*)(sBg + bw[j]) = uint2{ pk2(g0[j], g1[j]), pk2(g2[j], g3[j]) };
      *(uint2*)(sBu + bw[j]) = uint2{ pk2(u0[j], u1[j]), pk2(u2[j], u3[j]) };
    }
    softbar();
    if (kt + 1 < 32){
      const f4* p = (const f4*)(gsrc + (size_t)(kt + 1) * 64 * ID);
      g0 = p[0]; g1 = p[ID/4]; g2 = p[ID/2]; g3 = p[3*ID/4];
      const f4* q = (const f4*)(usrc + (size_t)(kt + 1) * 64 * ID);
      u0 = q[0]; u1 = q[ID/4]; u2 = q[ID/2]; u3 = q[3*ID/4];
    }
    const char* A = &sA[kt & 1][0];
#pragma unroll
    for (int ks = 0; ks < 2; ks++){
      short8 af[4];
#pragma unroll
      for (int f = 0; f < 4; f++) af[f] = *(const short8*)(A + aoff[ks][f]);
#pragma unroll
      for (int fn = 0; fn < 2; fn++){
        short8 bg = *(const short8*)(sBg + boff[ks][fn]);
        short8 bu = *(const short8*)(sBu + boff[ks][fn]);
#pragma unroll
        for (int fm = 0; fm < 4; fm++){
          accg[fm][fn] = __builtin_amdgcn_mfma_f32_16x16x32_bf16(af[fm], bg, accg[fm][fn], 0, 0, 0);
          accu[fm][fn] = __builtin_amdgcn_mfma_f32_16x16x32_bf16(af[fm], bu, accu[fm][fn], 0, 0, 0);
        }
      }
    }
  }
#pragma unroll
  for (int fm = 0; fm < 4; fm++){
#pragma unroll
    for (int r = 0; r < 4; r++){
      int row = wm * 64 + fm * 16 + (lane >> 4) * 4 + r;
      if (row < cntL){
        size_t base = (size_t)(p0 + row) * ID + (size_t)nt * 64 + wn * 32 + ln;
#pragma unroll
        for (int fn = 0; fn < 2; fn++){
          float g = accg[fm][fn][r];
          float u = accu[fm][fn][r];
          hbuf[base + fn * 16] = __float2bfloat16(gelu_t(g) * u);
        }
      }
    }
  }
}

__global__ __launch_bounds__(256, 3)
void k_down_r3(const __hip_bfloat16* __restrict__ hbuf, const float* __restrict__ Wd,
               const int* __restrict__ row_tok, const float* __restrict__ row_w,
               const int* __restrict__ off, float* __restrict__ out){
  __shared__ __align__(16) char sA[2][16384];
  __shared__ __align__(16) char sB[16384];
  __shared__ int s_tok[128];
  __shared__ float s_w[128];

  const int bid = blockIdx.x;
  const int e  = bid & 7;
  const int mt = (bid >> 3) & 7;
  const int nt = bid >> 6;
  const int o0 = off[e], cnt = off[e + 1] - o0;
  if (mt * 128 >= cnt) return;
  const int p0 = o0 + mt * 128;
  const int cntL = min(128, cnt - mt * 128);
  const int tid = threadIdx.x;
  const int wid = tid >> 6, lane = tid & 63;

  if (tid < 128){
    int p = min(p0 + tid, TT*2 - 1);
    s_tok[tid] = row_tok[p];
    s_w[tid]   = row_w[p];
  }
  __syncthreads();

  const char* asrc[4];
#pragma unroll
  for (int i = 0; i < 4; i++){
    int c = wid * 4 + i;
    int r = c * 8 + (lane >> 3);
    int p = min(p0 + r, TT*2 - 1);
    asrc[i] = (const char*)hbuf + (size_t)p * (ID * 2)
            + ((((lane & 7) ^ (lane >> 3)) & 7) << 4);
  }
  const int n0 = (tid & 31) * 4;
  const int k0 = (tid >> 5) * 8;
  const float* bsrc = Wd + (size_t)e * ID * HD + (size_t)k0 * HD + (size_t)nt * 128 + n0;
  int bw[4];
#pragma unroll
  for (int j = 0; j < 4; j++)
    bw[j] = (n0 + j) * 128 + ((((k0 >> 3) ^ (tid & 7) ^ (j << 1)) & 7) << 4);

  const int wm = wid >> 1, wn = wid & 1;
  const int kg = lane >> 4, ln = lane & 15;
  int aoff[2][4], boff[2][4];
#pragma unroll
  for (int ks = 0; ks < 2; ks++){
    int qs = ks * 4 + kg;
#pragma unroll
    for (int f = 0; f < 4; f++){
      int m = wm * 64 + f * 16 + ln;
      aoff[ks][f] = m * 128 + (((qs ^ (ln & 7)) & 7) << 4);
      int n = wn * 64 + f * 16 + ln;
      boff[ks][f] = n * 128 + (((qs ^ swzB(n)) & 7) << 4);
    }
  }

  f4 acc[4][4];
#pragma unroll
  for (int a = 0; a < 4; a++)
#pragma unroll
    for (int b = 0; b < 4; b++) acc[a][b] = f4{0,0,0,0};

#pragma unroll
  for (int i = 0; i < 4; i++) glds16(asrc[i], &sA[0][(wid * 4 + i) * 1024]);
  f4 r0, r1, r2, r3, r4, r5, r6, r7;
  { const f4* p = (const f4*)bsrc;
    r0 = p[0]; r1 = p[HD/4]; r2 = p[HD/2]; r3 = p[3*HD/4];
    r4 = p[HD]; r5 = p[5*HD/4]; r6 = p[3*HD/2]; r7 = p[7*HD/4]; }

  for (int kt = 0; kt < 32; ++kt){
    softbar();
    if (kt + 1 < 32){
      char* dst = &sA[(kt + 1) & 1][0] + (wid * 4) * 1024;
#pragma unroll
      for (int i = 0; i < 4; i++) glds16(asrc[i] + (size_t)(kt + 1) * 128, dst + i * 1024);
    }
#pragma unroll
    for (int j = 0; j < 4; j++){
      *(uint4*)(sB + bw[j]) = uint4{ pk2(r0[j], r1[j]), pk2(r2[j], r3[j]),
                                     pk2(r4[j], r5[j]), pk2(r6[j], r7[j]) };
    }
    softbar();
    if (kt + 1 < 32){
      const f4* p = (const f4*)(bsrc + (size_t)(kt + 1) * 64 * HD);
      r0 = p[0]; r1 = p[HD/4]; r2 = p[HD/2]; r3 = p[3*HD/4];
      r4 = p[HD]; r5 = p[5*HD/4]; r6 = p[3*HD/2]; r7 = p[7*HD/4];
    }
    const char* A = &sA[kt & 1][0];
#pragma unroll
    for (int ks = 0; ks < 2; ks++){
      short8 af[4];
#pragma unroll
      for (int f = 0; f < 4; f++) af[f] = *(const short8*)(A + aoff[ks][f]);
#pragma unroll
      for (int fn = 0; fn < 4; fn++){
        short8 bf = *(const short8*)(sB + boff[ks][fn]);
#pragma unroll
        for (int fm = 0; fm < 4; fm++)
          acc[fm][fn] = __builtin_amdgcn_mfma_f32_16x16x32_bf16(af[fm], bf, acc[fm][fn], 0, 0, 0);
      }
    }
  }
#pragma unroll
  for (int fm = 0; fm < 4; fm++){
#pragma unroll
    for (int r = 0; r < 4; r++){
      int row = wm * 64 + fm * 16 + (lane >> 4) * 4 + r;
      if (row < cntL){
        int tok = s_tok[row];
        float w = s_w[row];
        float* ob = out + (size_t)tok * HD + (size_t)nt * 128 + wn * 64 + ln;
#pragma unroll
        for (int fn = 0; fn < 4; fn++)
          atomicAdd(ob + fn * 16, acc[fm][fn][r] * w);
      }
    }
  }
}

extern "C" void kernel_launch(void* const* d_in, const int* in_sizes, int n_in,
                              void* d_out, int out_size, void* d_ws, size_t ws_size,
                              hipStream_t stream){
  (void)in_sizes; (void)n_in; (void)out_size;
  const float* X  = (const float*)d_in[0];
  const float* RL = (const float*)d_in[1];
  const float* SC = (const float*)d_in[2];
  const float* Wg = (const float*)d_in[3];
  const float* Wu = (const float*)d_in[4];
  const float* Wd = (const float*)d_in[5];
  float* out = (float*)d_out;

  char* ws = (char*)d_ws;
  int*   rid     = (int*)(ws);
  float* rw      = (float*)(ws + 16384);
  int*   row_tok = (int*)(ws + 32768);
  float* row_w   = (float*)(ws + 49152);
  int*   off     = (int*)(ws + 65536);
  __hip_bfloat16* hbuf = (__hip_bfloat16*)(ws + 66560);                      // 16 MiB
  __hip_bfloat16* Xb   = (__hip_bfloat16*)(ws + 66560 + 16777216ull);        // 8 MiB
  __hip_bfloat16* Wb   = (__hip_bfloat16*)(ws + 66560 + 16777216ull + 8388608ull);
  const size_t WME = (size_t)NE * 2048 * 2048;                               // elems per tensor
  const size_t GU  = 2 * WME;                                                // gu region elems
  const size_t need = 66560ull + 16777216ull + 8388608ull + 3ull * WME * 2ull;

  hipMemsetAsync(d_out, 0, (size_t)TT * HD * sizeof(float), stream);
  k_cvtx <<<2048, 256, 0, stream>>>(X, Xb);
  k_route<<<TT / 256, 256, 0, stream>>>(RL, SC, rid, rw);
  k_lists<<<1, 64, 0, stream>>>(rid, rw, row_tok, row_w, off);

  if (ws_size >= need){
    k_cvtw<<<24576, 256, 0, stream>>>(Wg, Wu, Wd, Wb);
    k_gu97<<<1280, 256, 0, stream>>>(Xb, Wb, row_tok, off, hbuf);
    k_dn97<<< 640, 256, 0, stream>>>(hbuf, Wb + GU, row_tok, row_w, off, out);
  } else {
    k_gateup_r3<<<2048, 256, 0, stream>>>(Xb, Wg, Wu, row_tok, off, hbuf);
    k_down_r3  <<<1024, 256, 0, stream>>>(hbuf, Wd, row_tok, row_w, off, out);
  }
}

// Round 14
// 325.044 us; speedup vs baseline: 1.4585x; 1.0885x over previous
//
#include <hip/hip_runtime.h>
#include <hip/hip_bf16.h>

#define TT 2048
#define HD 2048
#define ID 2048
#define NE 8

typedef __attribute__((ext_vector_type(8))) short short8;
typedef __attribute__((ext_vector_type(4))) float f4;

__device__ __forceinline__ unsigned short b16(float f){
  union { __hip_bfloat16 b; unsigned short u; } x;
  x.b = __float2bfloat16(f);
  return x.u;
}
__device__ __forceinline__ unsigned pk2(float lo, float hi){
  return (unsigned)b16(lo) | ((unsigned)b16(hi) << 16);
}
__device__ __forceinline__ float gelu_t(float x){
  float y = 0.7978845608028654f * (x + 0.044715f * x * x * x);
  float t = 1.0f - 2.0f / (__expf(2.0f * y) + 1.0f);
  return 0.5f * x * (1.0f + t);
}
__device__ __forceinline__ void glds16(const void* g, void* l){
  __builtin_amdgcn_global_load_lds(
      (const __attribute__((address_space(1))) unsigned*)g,
      (__attribute__((address_space(3))) unsigned*)l, 16, 0, 0);
}
__device__ __forceinline__ void softbar(){
  asm volatile("s_waitcnt lgkmcnt(0)" ::: "memory");
  __builtin_amdgcn_s_barrier();
  __builtin_amdgcn_sched_barrier(0);
}

// ---------------- X fp32 -> bf16 ----------------
__global__ void k_cvtx(const float* __restrict__ X, __hip_bfloat16* __restrict__ Xb){
  int i = blockIdx.x * 256 + threadIdx.x;
  const f4* src = (const f4*)X + (size_t)i * 2;
  f4 a = src[0], b = src[1];
  uint4 o = { pk2(a[0],a[1]), pk2(a[2],a[3]), pk2(b[0],b[1]), pk2(b[2],b[3]) };
  ((uint4*)Xb)[i] = o;
}

// ---------------- routing ----------------
__global__ void k_route(const float* __restrict__ lg, const float* __restrict__ sc,
                        int* __restrict__ rid, float* __restrict__ rw){
  int t = blockIdx.x * blockDim.x + threadIdx.x;
  if (t >= TT) return;
  float l[NE];
#pragma unroll
  for (int e = 0; e < NE; e++) l[e] = lg[t * NE + e];
  float mx = l[0];
#pragma unroll
  for (int e = 1; e < NE; e++) mx = fmaxf(mx, l[e]);
  float p[NE];
#pragma unroll
  for (int e = 0; e < NE; e++) p[e] = __expf(l[e] - mx);
  int i0 = 0; float b0 = l[0];
#pragma unroll
  for (int e = 1; e < NE; e++) if (l[e] > b0){ b0 = l[e]; i0 = e; }
  int i1 = -1; float b1 = -1e30f;
#pragma unroll
  for (int e = 0; e < NE; e++) if (e != i0 && l[e] > b1){ b1 = l[e]; i1 = e; }
  float p0 = p[i0], p1 = p[i1];
  float rn = p0 + p1; rn = (rn > 0.f) ? rn : 1.f;
  rw[t*2]   = p0 / rn * sc[i0];
  rw[t*2+1] = p1 / rn * sc[i1];
  rid[t*2]  = i0;
  rid[t*2+1]= i1;
}

// ---------------- deterministic per-expert compaction ----------------
__global__ void k_lists(const int* __restrict__ rid, const float* __restrict__ rw,
                        int* __restrict__ row_tok, float* __restrict__ row_w,
                        int* __restrict__ off){
  int lane = threadIdx.x;            // 64 threads
  int ids[64]; float wv[64];
#pragma unroll
  for (int i = 0; i < 64; i++) ids[i] = rid[i * 64 + lane];
#pragma unroll
  for (int i = 0; i < 64; i++) wv[i] = rw[i * 64 + lane];
  int cnt[NE];
#pragma unroll
  for (int e = 0; e < NE; e++) cnt[e] = 0;
#pragma unroll
  for (int i = 0; i < 64; i++){
#pragma unroll
    for (int e = 0; e < NE; e++)
      cnt[e] += __popcll(__ballot(ids[i] == e));
  }
  int offs[NE + 1]; offs[0] = 0;
#pragma unroll
  for (int e = 0; e < NE; e++) offs[e + 1] = offs[e] + cnt[e];
  if (lane == 0){
#pragma unroll
    for (int e = 0; e <= NE; e++) off[e] = offs[e];
  }
  int run[NE];
#pragma unroll
  for (int e = 0; e < NE; e++) run[e] = offs[e];
  unsigned long long ltm = (1ULL << lane) - 1ULL;
#pragma unroll
  for (int i = 0; i < 64; i++){
    int id = ids[i];
    int tok = (i * 64 + lane) >> 1;
#pragma unroll
    for (int e = 0; e < NE; e++){
      unsigned long long m = __ballot(id == e);
      if (id == e){
        int pos = run[e] + __popcll(m & ltm);
        row_tok[pos] = tok;
        row_w[pos]   = wv[i];
      }
      run[e] += __popcll(m);
    }
  }
}

// ================= FAST PATH: m97 schedule, fused fp32-W conversion in B-staging =============
// A: bf16 via glds16 (source-swizzled). B: fp32 [k][n] -> reg 4x4 transpose -> cvt_pk ->
// ds_write into [n'][64k] bf16, slot' = s ^ (n'&7). Depth-1 B prefetch, counted vmcnt(8).
// ISSUE ORDER PINNED with sched_barrier(0) between groups (round-13 lesson: counted vmcnt
// is only sound when the vmcnt-class issue order is pinned): ds_write B(kt) -> glds A(kt)x4
// -> B(kt+1)x8 -> vmcnt(8) drains exactly A.

// -------- gate+up: ONE grouped GEMM, g/u 32-col interleave in LDS n', fused gelu --------
__global__ __launch_bounds__(256, 3)
void k_gu_f(const __hip_bfloat16* __restrict__ Xb, const float* __restrict__ Wg,
            const float* __restrict__ Wu, const int* __restrict__ row_tok,
            const int* __restrict__ off, __hip_bfloat16* __restrict__ hbuf){
  __shared__ __align__(16) char sA[16384];   // [128 m][64 k] bf16, swizzled
  __shared__ __align__(16) char sB[16384];   // [128 n'][64 k] bf16, swizzled
  __shared__ int s_tok[128];

  const int bid = blockIdx.x;                // 1280 = e(bid&7) x 5mt x 32nt, mt inner
  const int e  = bid & 7;
  const int t  = bid >> 3;
  const int mt = t % 5;
  const int nt = t / 5;                      // 0..31: 64 g-cols + 64 u-cols per tile
  const int o0 = off[e], cnt = off[e + 1] - o0;
  if (mt * 128 >= cnt) return;
  const int p0 = o0 + mt * 128;
  const int cntL = min(128, cnt - mt * 128);
  const int tid = threadIdx.x;
  const int wid = tid >> 6, lane = tid & 63;

  if (tid < 128) s_tok[tid] = row_tok[min(p0 + tid, TT*2 - 1)];
  __syncthreads();

  // A staging sources (glds16, inverse-swizzled source)
  const int sw = (((lane & 7) ^ (lane >> 3)) & 7) << 4;
  const char* asrc[4];
#pragma unroll
  for (int i = 0; i < 4; i++){
    int r = (wid * 4 + i) * 8 + (lane >> 3);                // 0..127
    asrc[i] = (const char*)Xb + (size_t)s_tok[r] * 4096 + sw;
  }
  // B staging: thread -> matrix m2 (0=g,1=u), 4 n x 8 k (two k-quads)
  const int m2 = tid >> 7, tt = tid & 127;
  const int n0 = (tt & 15) * 4;              // 0..60 within 64-col panel
  const int k0 = (tt >> 4) * 4;              // 0..28
  const float* wsrc = (m2 ? Wu : Wg) + (size_t)e * HD * ID
                    + (size_t)k0 * ID + (size_t)nt * 64 + n0;
  int bw0[4], bw1[4];
#pragma unroll
  for (int j = 0; j < 4; j++){
    int n  = n0 + j;
    int np = (n >> 5) * 64 + (n & 31) + m2 * 32;            // gu-interleaved LDS row
    int s0 = k0 >> 3;                                       // k-slot 0..3
    int sub = (k0 & 4) << 1;                                // 0 or 8 bytes within slot
    bw0[j] = np * 128 + (((s0      ) ^ (np & 7)) << 4) + sub;
    bw1[j] = np * 128 + (((s0 ^ 4 ) ^ (np & 7)) << 4) + sub;
  }
  // fragment read offsets (r11-verified)
  const int wm = wid >> 1, wn = wid & 1;     // 2x2 waves, wave = 64m x 64n'
  const int kg = lane >> 4, ln = lane & 15;
  int aoff[4], boff[4];
#pragma unroll
  for (int f = 0; f < 4; f++){
    int m = wm * 64 + f * 16 + ln;
    aoff[f] = m * 128 + (((kg ^ (m & 7)) & 7) << 4);
    int n = wn * 64 + f * 16 + ln;
    boff[f] = n * 128 + (((kg ^ (n & 7)) & 7) << 4);
  }

  f4 acc[4][4];
#pragma unroll
  for (int a = 0; a < 4; a++)
#pragma unroll
    for (int b = 0; b < 4; b++) acc[a][b] = f4{0,0,0,0};

  // prologue: B(0) -> regs
  f4 r0, r1, r2, r3, r4, r5, r6, r7;
  { const float* p = wsrc;
    r0 = *(const f4*)(p);          r1 = *(const f4*)(p + ID);
    r2 = *(const f4*)(p + 2*ID);   r3 = *(const f4*)(p + 3*ID);
    r4 = *(const f4*)(p + 32*ID);  r5 = *(const f4*)(p + 33*ID);
    r6 = *(const f4*)(p + 34*ID);  r7 = *(const f4*)(p + 35*ID); }

  for (int kt = 0; kt < 32; ++kt){
    softbar();                                  // all waves done reading prev tiles
    // group 1: ds_write B(kt) (compiler inserts exact vmcnt dep-wait on B(kt) loads)
#pragma unroll
    for (int j = 0; j < 4; j++){
      *(uint2*)(sB + bw0[j]) = uint2{ pk2(r0[j], r1[j]), pk2(r2[j], r3[j]) };
      *(uint2*)(sB + bw1[j]) = uint2{ pk2(r4[j], r5[j]), pk2(r6[j], r7[j]) };
    }
    __builtin_amdgcn_sched_barrier(0);
    // group 2: glds A(kt) x4  (vmcnt 0 -> 4)
    { const int _o = kt * 128;
#pragma unroll
      for (int i = 0; i < 4; i++) glds16(asrc[i] + _o, sA + (wid * 4 + i) * 1024);
    }
    __builtin_amdgcn_sched_barrier(0);
    // group 3: prefetch B(kt+1) regs (vmcnt 4 -> 12)
    if (kt + 1 < 32){
      const float* p = wsrc + (size_t)(kt + 1) * 64 * ID;
      r0 = *(const f4*)(p);          r1 = *(const f4*)(p + ID);
      r2 = *(const f4*)(p + 2*ID);   r3 = *(const f4*)(p + 3*ID);
      r4 = *(const f4*)(p + 32*ID);  r5 = *(const f4*)(p + 33*ID);
      r6 = *(const f4*)(p + 34*ID);  r7 = *(const f4*)(p + 35*ID);
    }
    __builtin_amdgcn_sched_barrier(0);
    if (kt + 1 < 32){
      asm volatile("s_waitcnt vmcnt(8) lgkmcnt(0)" ::: "memory");  // drain A(kt)+ds_writes; B(kt+1) in flight
    } else {
      asm volatile("s_waitcnt vmcnt(0) lgkmcnt(0)" ::: "memory");
    }
    __builtin_amdgcn_s_barrier();
    __builtin_amdgcn_sched_barrier(0);
#pragma unroll
    for (int ks = 0; ks < 2; ks++){
      const int kx = ks * 64;
      short8 af[4], bf[4];
#pragma unroll
      for (int f = 0; f < 4; f++) af[f] = *(const short8*)(sA + (aoff[f] ^ kx));
#pragma unroll
      for (int f = 0; f < 4; f++) bf[f] = *(const short8*)(sB + (boff[f] ^ kx));
#pragma unroll
      for (int fn = 0; fn < 4; fn++)
#pragma unroll
        for (int fm = 0; fm < 4; fm++)
          acc[fm][fn] = __builtin_amdgcn_mfma_f32_16x16x32_bf16(af[fm], bf[fn], acc[fm][fn], 0, 0, 0);
    }
  }
  // epilogue: fn 0,1 = g cols, fn 2,3 = u cols of the SAME h columns
#pragma unroll
  for (int fm = 0; fm < 4; fm++){
#pragma unroll
    for (int r = 0; r < 4; r++){
      int row = wm * 64 + fm * 16 + (lane >> 4) * 4 + r;
      if (row < cntL){
        size_t base = (size_t)(p0 + row) * ID + (size_t)nt * 64 + wn * 32 + ln;
#pragma unroll
        for (int fn = 0; fn < 2; fn++){
          float g = acc[fm][fn][r];
          float u = acc[fm][fn + 2][r];
          hbuf[base + fn * 16] = __float2bfloat16(gelu_t(g) * u);
        }
      }
    }
  }
}

// -------- down: fused fp32 Wd staging + weighted atomic scatter --------
__global__ __launch_bounds__(256, 3)
void k_dn_f(const __hip_bfloat16* __restrict__ hbuf, const float* __restrict__ Wd,
            const int* __restrict__ row_tok, const float* __restrict__ row_w,
            const int* __restrict__ off, float* __restrict__ out){
  __shared__ __align__(16) char sA[16384];   // [128 m][64 k]
  __shared__ __align__(16) char sB[16384];   // [128 n][64 k]
  __shared__ int s_tok[128];
  __shared__ float s_w[128];

  const int bid = blockIdx.x;                // 640 = e(bid&7) x 5mt x 16nt
  const int e  = bid & 7;
  const int t  = bid >> 3;
  const int mt = t % 5;
  const int nt = t / 5;                      // 0..15
  const int o0 = off[e], cnt = off[e + 1] - o0;
  if (mt * 128 >= cnt) return;
  const int p0 = o0 + mt * 128;
  const int cntL = min(128, cnt - mt * 128);
  const int tid = threadIdx.x;
  const int wid = tid >> 6, lane = tid & 63;

  if (tid < 128){
    int p = min(p0 + tid, TT*2 - 1);
    s_tok[tid] = row_tok[p];
    s_w[tid]   = row_w[p];
  }
  __syncthreads();

  const int sw = (((lane & 7) ^ (lane >> 3)) & 7) << 4;
  const char* asrc[4];
#pragma unroll
  for (int i = 0; i < 4; i++){
    int r = (wid * 4 + i) * 8 + (lane >> 3);
    int p = min(p0 + r, TT*2 - 1);
    asrc[i] = (const char*)hbuf + (size_t)p * 4096 + sw;
  }
  // B staging: thread -> 4 n x 8 k of Wd [k][HD n]
  const int n0 = (tid & 31) * 4;             // 0..124
  const int k0 = (tid >> 5) * 4;             // 0..28
  const float* wsrc = Wd + (size_t)e * ID * HD + (size_t)k0 * HD + (size_t)nt * 128 + n0;
  int bw0[4], bw1[4];
#pragma unroll
  for (int j = 0; j < 4; j++){
    int np = n0 + j;
    int s0 = k0 >> 3;
    int sub = (k0 & 4) << 1;
    bw0[j] = np * 128 + (((s0     ) ^ (np & 7)) << 4) + sub;
    bw1[j] = np * 128 + (((s0 ^ 4) ^ (np & 7)) << 4) + sub;
  }
  const int wm = wid >> 1, wn = wid & 1;
  const int kg = lane >> 4, ln = lane & 15;
  int aoff[4], boff[4];
#pragma unroll
  for (int f = 0; f < 4; f++){
    int m = wm * 64 + f * 16 + ln;
    aoff[f] = m * 128 + (((kg ^ (m & 7)) & 7) << 4);
    int n = wn * 64 + f * 16 + ln;
    boff[f] = n * 128 + (((kg ^ (n & 7)) & 7) << 4);
  }

  f4 acc[4][4];
#pragma unroll
  for (int a = 0; a < 4; a++)
#pragma unroll
    for (int b = 0; b < 4; b++) acc[a][b] = f4{0,0,0,0};

  f4 r0, r1, r2, r3, r4, r5, r6, r7;
  { const float* p = wsrc;
    r0 = *(const f4*)(p);          r1 = *(const f4*)(p + HD);
    r2 = *(const f4*)(p + 2*HD);   r3 = *(const f4*)(p + 3*HD);
    r4 = *(const f4*)(p + 32*HD);  r5 = *(const f4*)(p + 33*HD);
    r6 = *(const f4*)(p + 34*HD);  r7 = *(const f4*)(p + 35*HD); }

  for (int kt = 0; kt < 32; ++kt){
    softbar();
#pragma unroll
    for (int j = 0; j < 4; j++){
      *(uint2*)(sB + bw0[j]) = uint2{ pk2(r0[j], r1[j]), pk2(r2[j], r3[j]) };
      *(uint2*)(sB + bw1[j]) = uint2{ pk2(r4[j], r5[j]), pk2(r6[j], r7[j]) };
    }
    __builtin_amdgcn_sched_barrier(0);
    { const int _o = kt * 128;
#pragma unroll
      for (int i = 0; i < 4; i++) glds16(asrc[i] + _o, sA + (wid * 4 + i) * 1024);
    }
    __builtin_amdgcn_sched_barrier(0);
    if (kt + 1 < 32){
      const float* p = wsrc + (size_t)(kt + 1) * 64 * HD;
      r0 = *(const f4*)(p);          r1 = *(const f4*)(p + HD);
      r2 = *(const f4*)(p + 2*HD);   r3 = *(const f4*)(p + 3*HD);
      r4 = *(const f4*)(p + 32*HD);  r5 = *(const f4*)(p + 33*HD);
      r6 = *(const f4*)(p + 34*HD);  r7 = *(const f4*)(p + 35*HD);
    }
    __builtin_amdgcn_sched_barrier(0);
    if (kt + 1 < 32){
      asm volatile("s_waitcnt vmcnt(8) lgkmcnt(0)" ::: "memory");
    } else {
      asm volatile("s_waitcnt vmcnt(0) lgkmcnt(0)" ::: "memory");
    }
    __builtin_amdgcn_s_barrier();
    __builtin_amdgcn_sched_barrier(0);
#pragma unroll
    for (int ks = 0; ks < 2; ks++){
      const int kx = ks * 64;
      short8 af[4], bf[4];
#pragma unroll
      for (int f = 0; f < 4; f++) af[f] = *(const short8*)(sA + (aoff[f] ^ kx));
#pragma unroll
      for (int f = 0; f < 4; f++) bf[f] = *(const short8*)(sB + (boff[f] ^ kx));
#pragma unroll
      for (int fn = 0; fn < 4; fn++)
#pragma unroll
        for (int fm = 0; fm < 4; fm++)
          acc[fm][fn] = __builtin_amdgcn_mfma_f32_16x16x32_bf16(af[fm], bf[fn], acc[fm][fn], 0, 0, 0);
    }
  }
#pragma unroll
  for (int fm = 0; fm < 4; fm++){
#pragma unroll
    for (int r = 0; r < 4; r++){
      int row = wm * 64 + fm * 16 + (lane >> 4) * 4 + r;
      if (row < cntL){
        int tok = s_tok[row];
        float w = s_w[row];
        float* ob = out + (size_t)tok * HD + (size_t)nt * 128 + wn * 64 + ln;
#pragma unroll
        for (int fn = 0; fn < 4; fn++)
          atomicAdd(ob + fn * 16, acc[fm][fn][r] * w);
      }
    }
  }
}

extern "C" void kernel_launch(void* const* d_in, const int* in_sizes, int n_in,
                              void* d_out, int out_size, void* d_ws, size_t ws_size,
                              hipStream_t stream){
  (void)in_sizes; (void)n_in; (void)out_size; (void)ws_size;
  const float* X  = (const float*)d_in[0];
  const float* RL = (const float*)d_in[1];
  const float* SC = (const float*)d_in[2];
  const float* Wg = (const float*)d_in[3];
  const float* Wu = (const float*)d_in[4];
  const float* Wd = (const float*)d_in[5];
  float* out = (float*)d_out;

  char* ws = (char*)d_ws;
  int*   rid     = (int*)(ws);
  float* rw      = (float*)(ws + 16384);
  int*   row_tok = (int*)(ws + 32768);
  float* row_w   = (float*)(ws + 49152);
  int*   off     = (int*)(ws + 65536);
  __hip_bfloat16* hbuf = (__hip_bfloat16*)(ws + 66560);                      // 16 MiB
  __hip_bfloat16* Xb   = (__hip_bfloat16*)(ws + 66560 + 16777216ull);        // 8 MiB

  hipMemsetAsync(d_out, 0, (size_t)TT * HD * sizeof(float), stream);
  k_cvtx <<<2048, 256, 0, stream>>>(X, Xb);
  k_route<<<TT / 256, 256, 0, stream>>>(RL, SC, rid, rw);
  k_lists<<<1, 64, 0, stream>>>(rid, rw, row_tok, row_w, off);
  k_gu_f<<<1280, 256, 0, stream>>>(Xb, Wg, Wu, row_tok, off, hbuf);
  k_dn_f<<< 640, 256, 0, stream>>>(hbuf, Wd, row_tok, row_w, off, out);
}

// Round 15
// 313.710 us; speedup vs baseline: 1.5112x; 1.0361x over previous
//
#include <hip/hip_runtime.h>
#include <hip/hip_bf16.h>

#define TT 2048
#define HD 2048
#define ID 2048
#define NE 8

typedef __attribute__((ext_vector_type(8))) short short8;
typedef __attribute__((ext_vector_type(4))) float f4;

__device__ __forceinline__ unsigned short b16(float f){
  union { __hip_bfloat16 b; unsigned short u; } x;
  x.b = __float2bfloat16(f);
  return x.u;
}
__device__ __forceinline__ unsigned pk2(float lo, float hi){
  return (unsigned)b16(lo) | ((unsigned)b16(hi) << 16);
}
__device__ __forceinline__ float gelu_t(float x){
  float y = 0.7978845608028654f * (x + 0.044715f * x * x * x);
  float t = 1.0f - 2.0f / (__expf(2.0f * y) + 1.0f);
  return 0.5f * x * (1.0f + t);
}
__device__ __forceinline__ void glds16(const void* g, void* l){
  __builtin_amdgcn_global_load_lds(
      (const __attribute__((address_space(1))) unsigned*)g,
      (__attribute__((address_space(3))) unsigned*)l, 16, 0, 0);
}
__device__ __forceinline__ void softbar(){
  asm volatile("s_waitcnt lgkmcnt(0)" ::: "memory");
  __builtin_amdgcn_s_barrier();
  __builtin_amdgcn_sched_barrier(0);
}
// B-side swizzle: per-lane-varying ((np>>2)&7) spreads ds_writes to the bank floor;
// reads stay at floor (2 lanes/slot/kg-group).
__device__ __forceinline__ int swzB2(int np){ return (((np >> 2) & 7) ^ ((np & 3) << 1)) & 7; }

// ---------------- X fp32 -> bf16 ----------------
__global__ void k_cvtx(const float* __restrict__ X, __hip_bfloat16* __restrict__ Xb){
  int i = blockIdx.x * 256 + threadIdx.x;
  const f4* src = (const f4*)X + (size_t)i * 2;
  f4 a = src[0], b = src[1];
  uint4 o = { pk2(a[0],a[1]), pk2(a[2],a[3]), pk2(b[0],b[1]), pk2(b[2],b[3]) };
  ((uint4*)Xb)[i] = o;
}

// ---------------- routing ----------------
__global__ void k_route(const float* __restrict__ lg, const float* __restrict__ sc,
                        int* __restrict__ rid, float* __restrict__ rw){
  int t = blockIdx.x * blockDim.x + threadIdx.x;
  if (t >= TT) return;
  float l[NE];
#pragma unroll
  for (int e = 0; e < NE; e++) l[e] = lg[t * NE + e];
  float mx = l[0];
#pragma unroll
  for (int e = 1; e < NE; e++) mx = fmaxf(mx, l[e]);
  float p[NE];
#pragma unroll
  for (int e = 0; e < NE; e++) p[e] = __expf(l[e] - mx);
  int i0 = 0; float b0 = l[0];
#pragma unroll
  for (int e = 1; e < NE; e++) if (l[e] > b0){ b0 = l[e]; i0 = e; }
  int i1 = -1; float b1 = -1e30f;
#pragma unroll
  for (int e = 0; e < NE; e++) if (e != i0 && l[e] > b1){ b1 = l[e]; i1 = e; }
  float p0 = p[i0], p1 = p[i1];
  float rn = p0 + p1; rn = (rn > 0.f) ? rn : 1.f;
  rw[t*2]   = p0 / rn * sc[i0];
  rw[t*2+1] = p1 / rn * sc[i1];
  rid[t*2]  = i0;
  rid[t*2+1]= i1;
}

// ---------------- deterministic per-expert compaction ----------------
__global__ void k_lists(const int* __restrict__ rid, const float* __restrict__ rw,
                        int* __restrict__ row_tok, float* __restrict__ row_w,
                        int* __restrict__ off){
  int lane = threadIdx.x;            // 64 threads
  int ids[64]; float wv[64];
#pragma unroll
  for (int i = 0; i < 64; i++) ids[i] = rid[i * 64 + lane];
#pragma unroll
  for (int i = 0; i < 64; i++) wv[i] = rw[i * 64 + lane];
  int cnt[NE];
#pragma unroll
  for (int e = 0; e < NE; e++) cnt[e] = 0;
#pragma unroll
  for (int i = 0; i < 64; i++){
#pragma unroll
    for (int e = 0; e < NE; e++)
      cnt[e] += __popcll(__ballot(ids[i] == e));
  }
  int offs[NE + 1]; offs[0] = 0;
#pragma unroll
  for (int e = 0; e < NE; e++) offs[e + 1] = offs[e] + cnt[e];
  if (lane == 0){
#pragma unroll
    for (int e = 0; e <= NE; e++) off[e] = offs[e];
  }
  int run[NE];
#pragma unroll
  for (int e = 0; e < NE; e++) run[e] = offs[e];
  unsigned long long ltm = (1ULL << lane) - 1ULL;
#pragma unroll
  for (int i = 0; i < 64; i++){
    int id = ids[i];
    int tok = (i * 64 + lane) >> 1;
#pragma unroll
    for (int e = 0; e < NE; e++){
      unsigned long long m = __ballot(id == e);
      if (id == e){
        int pos = run[e] + __popcll(m & ltm);
        row_tok[pos] = tok;
        row_w[pos]   = wv[i];
      }
      run[e] += __popcll(m);
    }
  }
}

// ================= FAST PATH: m97 schedule, fused fp32-W conversion in B-staging =============
// A: bf16 via glds16 (source-swizzled, slot^=(m&7)). B: fp32 [k][n] -> reg 4x4 transpose ->
// cvt_pk -> ds_write into [n'][64k] bf16, physical slot = q ^ swzB2(n'). Depth-1 B prefetch,
// counted vmcnt(8), issue order pinned with sched_barrier(0) between vmcnt-class groups.

// -------- gate+up: ONE grouped GEMM, g/u 32-col interleave in LDS n', fused gelu --------
__global__ __launch_bounds__(256, 3)
void k_gu_f(const __hip_bfloat16* __restrict__ Xb, const float* __restrict__ Wg,
            const float* __restrict__ Wu, const int* __restrict__ row_tok,
            const int* __restrict__ off, __hip_bfloat16* __restrict__ hbuf){
  __shared__ __align__(16) char sA[16384];   // [128 m][64 k] bf16, slot^=(m&7)
  __shared__ __align__(16) char sB[16384];   // [128 n'][64 k] bf16, slot^=swzB2(n')
  __shared__ int s_tok[128];

  const int bid = blockIdx.x;                // 1280 = e(bid&7) x 5mt x 32nt, mt inner
  const int e  = bid & 7;
  const int t  = bid >> 3;
  const int mt = t % 5;
  const int nt = t / 5;                      // 0..31: 64 g-cols + 64 u-cols per tile
  const int o0 = off[e], cnt = off[e + 1] - o0;
  if (mt * 128 >= cnt) return;
  const int p0 = o0 + mt * 128;
  const int cntL = min(128, cnt - mt * 128);
  const int tid = threadIdx.x;
  const int wid = tid >> 6, lane = tid & 63;

  if (tid < 128) s_tok[tid] = row_tok[min(p0 + tid, TT*2 - 1)];
  __syncthreads();

  // A staging sources (glds16, inverse-swizzled source)
  const int sw = (((lane & 7) ^ (lane >> 3)) & 7) << 4;
  const char* asrc[4];
#pragma unroll
  for (int i = 0; i < 4; i++){
    int r = (wid * 4 + i) * 8 + (lane >> 3);                // 0..127
    asrc[i] = (const char*)Xb + (size_t)s_tok[r] * 4096 + sw;
  }
  // B staging: thread -> matrix m2 (0=g,1=u), 4 n x 8 k (two k-quads)
  const int m2 = tid >> 7, tt = tid & 127;
  const int n0 = (tt & 15) * 4;              // 0..60 within 64-col panel
  const int k0 = (tt >> 4) * 4;              // 0..28
  const float* wsrc = (m2 ? Wu : Wg) + (size_t)e * HD * ID
                    + (size_t)k0 * ID + (size_t)nt * 64 + n0;
  int bw0[4], bw1[4];
#pragma unroll
  for (int j = 0; j < 4; j++){
    int n  = n0 + j;
    int np = (n >> 5) * 64 + (n & 31) + m2 * 32;            // gu-interleaved LDS row
    int s0 = k0 >> 3;                                       // logical k-slot 0..3
    int sub = (k0 & 4) << 1;                                // 0 or 8 bytes within slot
    int F  = swzB2(np);
    bw0[j] = np * 128 + (((s0      ^ F) & 7) << 4) + sub;
    bw1[j] = np * 128 + (((s0 ^ 4  ^ F) & 7) << 4) + sub;
  }
  // fragment read offsets
  const int wm = wid >> 1, wn = wid & 1;     // 2x2 waves, wave = 64m x 64n'
  const int kg = lane >> 4, ln = lane & 15;
  int aoff[4], boff[4];
#pragma unroll
  for (int f = 0; f < 4; f++){
    int m = wm * 64 + f * 16 + ln;
    aoff[f] = m * 128 + (((kg ^ (m & 7)) & 7) << 4);
    int n = wn * 64 + f * 16 + ln;
    boff[f] = n * 128 + (((kg ^ swzB2(n)) & 7) << 4);
  }

  f4 acc[4][4];
#pragma unroll
  for (int a = 0; a < 4; a++)
#pragma unroll
    for (int b = 0; b < 4; b++) acc[a][b] = f4{0,0,0,0};

  // prologue: B(0) -> regs
  f4 r0, r1, r2, r3, r4, r5, r6, r7;
  { const float* p = wsrc;
    r0 = *(const f4*)(p);          r1 = *(const f4*)(p + ID);
    r2 = *(const f4*)(p + 2*ID);   r3 = *(const f4*)(p + 3*ID);
    r4 = *(const f4*)(p + 32*ID);  r5 = *(const f4*)(p + 33*ID);
    r6 = *(const f4*)(p + 34*ID);  r7 = *(const f4*)(p + 35*ID); }

  for (int kt = 0; kt < 32; ++kt){
    softbar();                                  // all waves done reading prev tiles
    // group 1: ds_write B(kt) (compiler inserts exact vmcnt dep-wait on B(kt) loads)
#pragma unroll
    for (int j = 0; j < 4; j++){
      *(uint2*)(sB + bw0[j]) = uint2{ pk2(r0[j], r1[j]), pk2(r2[j], r3[j]) };
      *(uint2*)(sB + bw1[j]) = uint2{ pk2(r4[j], r5[j]), pk2(r6[j], r7[j]) };
    }
    __builtin_amdgcn_sched_barrier(0);
    // group 2: glds A(kt) x4  (vmcnt 0 -> 4)
    { const int _o = kt * 128;
#pragma unroll
      for (int i = 0; i < 4; i++) glds16(asrc[i] + _o, sA + (wid * 4 + i) * 1024);
    }
    __builtin_amdgcn_sched_barrier(0);
    // group 3: prefetch B(kt+1) regs (vmcnt 4 -> 12)
    if (kt + 1 < 32){
      const float* p = wsrc + (size_t)(kt + 1) * 64 * ID;
      r0 = *(const f4*)(p);          r1 = *(const f4*)(p + ID);
      r2 = *(const f4*)(p + 2*ID);   r3 = *(const f4*)(p + 3*ID);
      r4 = *(const f4*)(p + 32*ID);  r5 = *(const f4*)(p + 33*ID);
      r6 = *(const f4*)(p + 34*ID);  r7 = *(const f4*)(p + 35*ID);
    }
    __builtin_amdgcn_sched_barrier(0);
    if (kt + 1 < 32){
      asm volatile("s_waitcnt vmcnt(8) lgkmcnt(0)" ::: "memory");  // drain A(kt)+writes; B(kt+1) in flight
    } else {
      asm volatile("s_waitcnt vmcnt(0) lgkmcnt(0)" ::: "memory");
    }
    __builtin_amdgcn_s_barrier();
    __builtin_amdgcn_sched_barrier(0);
#pragma unroll
    for (int ks = 0; ks < 2; ks++){
      const int kx = ks * 64;
      short8 af[4], bf[4];
#pragma unroll
      for (int f = 0; f < 4; f++) af[f] = *(const short8*)(sA + (aoff[f] ^ kx));
#pragma unroll
      for (int f = 0; f < 4; f++) bf[f] = *(const short8*)(sB + (boff[f] ^ kx));
#pragma unroll
      for (int fn = 0; fn < 4; fn++)
#pragma unroll
        for (int fm = 0; fm < 4; fm++)
          acc[fm][fn] = __builtin_amdgcn_mfma_f32_16x16x32_bf16(af[fm], bf[fn], acc[fm][fn], 0, 0, 0);
    }
  }
  // epilogue: fn 0,1 = g cols, fn 2,3 = u cols of the SAME h columns
#pragma unroll
  for (int fm = 0; fm < 4; fm++){
#pragma unroll
    for (int r = 0; r < 4; r++){
      int row = wm * 64 + fm * 16 + (lane >> 4) * 4 + r;
      if (row < cntL){
        size_t base = (size_t)(p0 + row) * ID + (size_t)nt * 64 + wn * 32 + ln;
#pragma unroll
        for (int fn = 0; fn < 2; fn++){
          float g = acc[fm][fn][r];
          float u = acc[fm][fn + 2][r];
          hbuf[base + fn * 16] = __float2bfloat16(gelu_t(g) * u);
        }
      }
    }
  }
}

// -------- down: fused fp32 Wd staging + weighted atomic scatter --------
__global__ __launch_bounds__(256, 3)
void k_dn_f(const __hip_bfloat16* __restrict__ hbuf, const float* __restrict__ Wd,
            const int* __restrict__ row_tok, const float* __restrict__ row_w,
            const int* __restrict__ off, float* __restrict__ out){
  __shared__ __align__(16) char sA[16384];   // [128 m][64 k]
  __shared__ __align__(16) char sB[16384];   // [128 n][64 k], slot^=swzB2(n)
  __shared__ int s_tok[128];
  __shared__ float s_w[128];

  const int bid = blockIdx.x;                // 640 = e(bid&7) x 5mt x 16nt
  const int e  = bid & 7;
  const int t  = bid >> 3;
  const int mt = t % 5;
  const int nt = t / 5;                      // 0..15
  const int o0 = off[e], cnt = off[e + 1] - o0;
  if (mt * 128 >= cnt) return;
  const int p0 = o0 + mt * 128;
  const int cntL = min(128, cnt - mt * 128);
  const int tid = threadIdx.x;
  const int wid = tid >> 6, lane = tid & 63;

  if (tid < 128){
    int p = min(p0 + tid, TT*2 - 1);
    s_tok[tid] = row_tok[p];
    s_w[tid]   = row_w[p];
  }
  __syncthreads();

  const int sw = (((lane & 7) ^ (lane >> 3)) & 7) << 4;
  const char* asrc[4];
#pragma unroll
  for (int i = 0; i < 4; i++){
    int r = (wid * 4 + i) * 8 + (lane >> 3);
    int p = min(p0 + r, TT*2 - 1);
    asrc[i] = (const char*)hbuf + (size_t)p * 4096 + sw;
  }
  // B staging: thread -> 4 n x 8 k of Wd [k][HD n]
  const int n0 = (tid & 31) * 4;             // 0..124
  const int k0 = (tid >> 5) * 4;             // 0..28
  const float* wsrc = Wd + (size_t)e * ID * HD + (size_t)k0 * HD + (size_t)nt * 128 + n0;
  int bw0[4], bw1[4];
#pragma unroll
  for (int j = 0; j < 4; j++){
    int np = n0 + j;
    int s0 = k0 >> 3;
    int sub = (k0 & 4) << 1;
    int F  = swzB2(np);
    bw0[j] = np * 128 + (((s0     ^ F) & 7) << 4) + sub;
    bw1[j] = np * 128 + (((s0 ^ 4 ^ F) & 7) << 4) + sub;
  }
  const int wm = wid >> 1, wn = wid & 1;
  const int kg = lane >> 4, ln = lane & 15;
  int aoff[4], boff[4];
#pragma unroll
  for (int f = 0; f < 4; f++){
    int m = wm * 64 + f * 16 + ln;
    aoff[f] = m * 128 + (((kg ^ (m & 7)) & 7) << 4);
    int n = wn * 64 + f * 16 + ln;
    boff[f] = n * 128 + (((kg ^ swzB2(n)) & 7) << 4);
  }

  f4 acc[4][4];
#pragma unroll
  for (int a = 0; a < 4; a++)
#pragma unroll
    for (int b = 0; b < 4; b++) acc[a][b] = f4{0,0,0,0};

  f4 r0, r1, r2, r3, r4, r5, r6, r7;
  { const float* p = wsrc;
    r0 = *(const f4*)(p);          r1 = *(const f4*)(p + HD);
    r2 = *(const f4*)(p + 2*HD);   r3 = *(const f4*)(p + 3*HD);
    r4 = *(const f4*)(p + 32*HD);  r5 = *(const f4*)(p + 33*HD);
    r6 = *(const f4*)(p + 34*HD);  r7 = *(const f4*)(p + 35*HD); }

  for (int kt = 0; kt < 32; ++kt){
    softbar();
#pragma unroll
    for (int j = 0; j < 4; j++){
      *(uint2*)(sB + bw0[j]) = uint2{ pk2(r0[j], r1[j]), pk2(r2[j], r3[j]) };
      *(uint2*)(sB + bw1[j]) = uint2{ pk2(r4[j], r5[j]), pk2(r6[j], r7[j]) };
    }
    __builtin_amdgcn_sched_barrier(0);
    { const int _o = kt * 128;
#pragma unroll
      for (int i = 0; i < 4; i++) glds16(asrc[i] + _o, sA + (wid * 4 + i) * 1024);
    }
    __builtin_amdgcn_sched_barrier(0);
    if (kt + 1 < 32){
      const float* p = wsrc + (size_t)(kt + 1) * 64 * HD;
      r0 = *(const f4*)(p);          r1 = *(const f4*)(p + HD);
      r2 = *(const f4*)(p + 2*HD);   r3 = *(const f4*)(p + 3*HD);
      r4 = *(const f4*)(p + 32*HD);  r5 = *(const f4*)(p + 33*HD);
      r6 = *(const f4*)(p + 34*HD);  r7 = *(const f4*)(p + 35*HD);
    }
    __builtin_amdgcn_sched_barrier(0);
    if (kt + 1 < 32){
      asm volatile("s_waitcnt vmcnt(8) lgkmcnt(0)" ::: "memory");
    } else {
      asm volatile("s_waitcnt vmcnt(0) lgkmcnt(0)" ::: "memory");
    }
    __builtin_amdgcn_s_barrier();
    __builtin_amdgcn_sched_barrier(0);
#pragma unroll
    for (int ks = 0; ks < 2; ks++){
      const int kx = ks * 64;
      short8 af[4], bf[4];
#pragma unroll
      for (int f = 0; f < 4; f++) af[f] = *(const short8*)(sA + (aoff[f] ^ kx));
#pragma unroll
      for (int f = 0; f < 4; f++) bf[f] = *(const short8*)(sB + (boff[f] ^ kx));
#pragma unroll
      for (int fn = 0; fn < 4; fn++)
#pragma unroll
        for (int fm = 0; fm < 4; fm++)
          acc[fm][fn] = __builtin_amdgcn_mfma_f32_16x16x32_bf16(af[fm], bf[fn], acc[fm][fn], 0, 0, 0);
    }
  }
#pragma unroll
  for (int fm = 0; fm < 4; fm++){
#pragma unroll
    for (int r = 0; r < 4; r++){
      int row = wm * 64 + fm * 16 + (lane >> 4) * 4 + r;
      if (row < cntL){
        int tok = s_tok[row];
        float w = s_w[row];
        float* ob = out + (size_t)tok * HD + (size_t)nt * 128 + wn * 64 + ln;
#pragma unroll
        for (int fn = 0; fn < 4; fn++)
          atomicAdd(ob + fn * 16, acc[fm][fn][r] * w);
      }
    }
  }
}

extern "C" void kernel_launch(void* const* d_in, const int* in_sizes, int n_in,
                              void* d_out, int out_size, void* d_ws, size_t ws_size,
                              hipStream_t stream){
  (void)in_sizes; (void)n_in; (void)out_size; (void)ws_size;
  const float* X  = (const float*)d_in[0];
  const float* RL = (const float*)d_in[1];
  const float* SC = (const float*)d_in[2];
  const float* Wg = (const float*)d_in[3];
  const float* Wu = (const float*)d_in[4];
  const float* Wd = (const float*)d_in[5];
  float* out = (float*)d_out;

  char* ws = (char*)d_ws;
  int*   rid     = (int*)(ws);
  float* rw      = (float*)(ws + 16384);
  int*   row_tok = (int*)(ws + 32768);
  float* row_w   = (float*)(ws + 49152);
  int*   off     = (int*)(ws + 65536);
  __hip_bfloat16* hbuf = (__hip_bfloat16*)(ws + 66560);                      // 16 MiB
  __hip_bfloat16* Xb   = (__hip_bfloat16*)(ws + 66560 + 16777216ull);        // 8 MiB

  hipMemsetAsync(d_out, 0, (size_t)TT * HD * sizeof(float), stream);
  k_cvtx <<<2048, 256, 0, stream>>>(X, Xb);
  k_route<<<TT / 256, 256, 0, stream>>>(RL, SC, rid, rw);
  k_lists<<<1, 64, 0, stream>>>(rid, rw, row_tok, row_w, off);
  k_gu_f<<<1280, 256, 0, stream>>>(Xb, Wg, Wu, row_tok, off, hbuf);
  k_dn_f<<< 640, 256, 0, stream>>>(hbuf, Wd, row_tok, row_w, off, out);
}

// Round 16
// 305.010 us; speedup vs baseline: 1.5543x; 1.0285x over previous
//
#include <hip/hip_runtime.h>
#include <hip/hip_bf16.h>

#define TT 2048
#define HD 2048
#define ID 2048
#define NE 8

typedef __attribute__((ext_vector_type(8))) short short8;
typedef __attribute__((ext_vector_type(4))) float f4;

__device__ __forceinline__ unsigned short b16(float f){
  union { __hip_bfloat16 b; unsigned short u; } x;
  x.b = __float2bfloat16(f);
  return x.u;
}
__device__ __forceinline__ unsigned pk2(float lo, float hi){
  return (unsigned)b16(lo) | ((unsigned)b16(hi) << 16);
}
__device__ __forceinline__ float gelu_t(float x){
  float y = 0.7978845608028654f * (x + 0.044715f * x * x * x);
  float t = 1.0f - 2.0f / (__expf(2.0f * y) + 1.0f);
  return 0.5f * x * (1.0f + t);
}
__device__ __forceinline__ void glds16(const void* g, void* l){
  __builtin_amdgcn_global_load_lds(
      (const __attribute__((address_space(1))) unsigned*)g,
      (__attribute__((address_space(3))) unsigned*)l, 16, 0, 0);
}
__device__ __forceinline__ void softbar(){
  asm volatile("s_waitcnt lgkmcnt(0)" ::: "memory");
  __builtin_amdgcn_s_barrier();
  __builtin_amdgcn_sched_barrier(0);
}
__device__ __forceinline__ int swzB2(int np){ return (((np >> 2) & 7) ^ ((np & 3) << 1)) & 7; }

// ---------------- X fp32 -> bf16 ----------------
__global__ void k_cvtx(const float* __restrict__ X, __hip_bfloat16* __restrict__ Xb){
  int i = blockIdx.x * 256 + threadIdx.x;
  const f4* src = (const f4*)X + (size_t)i * 2;
  f4 a = src[0], b = src[1];
  uint4 o = { pk2(a[0],a[1]), pk2(a[2],a[3]), pk2(b[0],b[1]), pk2(b[2],b[3]) };
  ((uint4*)Xb)[i] = o;
}

// ---------------- routing ----------------
__global__ void k_route(const float* __restrict__ lg, const float* __restrict__ sc,
                        int* __restrict__ rid, float* __restrict__ rw){
  int t = blockIdx.x * blockDim.x + threadIdx.x;
  if (t >= TT) return;
  float l[NE];
#pragma unroll
  for (int e = 0; e < NE; e++) l[e] = lg[t * NE + e];
  float mx = l[0];
#pragma unroll
  for (int e = 1; e < NE; e++) mx = fmaxf(mx, l[e]);
  float p[NE];
#pragma unroll
  for (int e = 0; e < NE; e++) p[e] = __expf(l[e] - mx);
  int i0 = 0; float b0 = l[0];
#pragma unroll
  for (int e = 1; e < NE; e++) if (l[e] > b0){ b0 = l[e]; i0 = e; }
  int i1 = -1; float b1 = -1e30f;
#pragma unroll
  for (int e = 0; e < NE; e++) if (e != i0 && l[e] > b1){ b1 = l[e]; i1 = e; }
  float p0 = p[i0], p1 = p[i1];
  float rn = p0 + p1; rn = (rn > 0.f) ? rn : 1.f;
  rw[t*2]   = p0 / rn * sc[i0];
  rw[t*2+1] = p1 / rn * sc[i1];
  rid[t*2]  = i0;
  rid[t*2+1]= i1;
}

// ---------------- deterministic per-expert compaction ----------------
__global__ void k_lists(const int* __restrict__ rid, const float* __restrict__ rw,
                        int* __restrict__ row_tok, float* __restrict__ row_w,
                        int* __restrict__ off){
  int lane = threadIdx.x;            // 64 threads
  int ids[64]; float wv[64];
#pragma unroll
  for (int i = 0; i < 64; i++) ids[i] = rid[i * 64 + lane];
#pragma unroll
  for (int i = 0; i < 64; i++) wv[i] = rw[i * 64 + lane];
  int cnt[NE];
#pragma unroll
  for (int e = 0; e < NE; e++) cnt[e] = 0;
#pragma unroll
  for (int i = 0; i < 64; i++){
#pragma unroll
    for (int e = 0; e < NE; e++)
      cnt[e] += __popcll(__ballot(ids[i] == e));
  }
  int offs[NE + 1]; offs[0] = 0;
#pragma unroll
  for (int e = 0; e < NE; e++) offs[e + 1] = offs[e] + cnt[e];
  if (lane == 0){
#pragma unroll
    for (int e = 0; e <= NE; e++) off[e] = offs[e];
  }
  int run[NE];
#pragma unroll
  for (int e = 0; e < NE; e++) run[e] = offs[e];
  unsigned long long ltm = (1ULL << lane) - 1ULL;
#pragma unroll
  for (int i = 0; i < 64; i++){
    int id = ids[i];
    int tok = (i * 64 + lane) >> 1;
#pragma unroll
    for (int e = 0; e < NE; e++){
      unsigned long long m = __ballot(id == e);
      if (id == e){
        int pos = run[e] + __popcll(m & ltm);
        row_tok[pos] = tok;
        row_w[pos]   = wv[i];
      }
      run[e] += __popcll(m);
    }
  }
}

// ================= FAST PATH: fused fp32-W conversion, A double-buffered ====================
// Schedule per iter (drain-at-ds_write; NO manual vmcnt):
//   softbar -> ds_write B(kt) [compiler dep-wait drains A(kt), issued 1 iter ago -> latency
//   covered] -> glds A(kt+1) -> sA[alt] -> load B(kt+1) regs -> lgkmcnt(0)+barrier -> MFMA.
// B: thread owns 4n x 8-consecutive-k -> 4x ds_write_b128, slot = (k0>>3) ^ swzB2(n').

// -------- gate+up: ONE grouped GEMM, g/u 32-col interleave in LDS n', fused gelu --------
__global__ __launch_bounds__(256, 3)
void k_gu_f(const __hip_bfloat16* __restrict__ Xb, const float* __restrict__ Wg,
            const float* __restrict__ Wu, const int* __restrict__ row_tok,
            const int* __restrict__ off, __hip_bfloat16* __restrict__ hbuf){
  __shared__ __align__(16) char sA[2][16384];  // [128 m][64 k] bf16, slot^=(m&7), dbuf
  __shared__ __align__(16) char sB[16384];     // [128 n'][64 k] bf16, slot^=swzB2(n')
  __shared__ int s_tok[128];

  const int bid = blockIdx.x;                // 1280 = e(bid&7) x 5mt x 32nt, mt inner
  const int e  = bid & 7;
  const int t  = bid >> 3;
  const int mt = t % 5;
  const int nt = t / 5;                      // 0..31: 64 g-cols + 64 u-cols per tile
  const int o0 = off[e], cnt = off[e + 1] - o0;
  if (mt * 128 >= cnt) return;
  const int p0 = o0 + mt * 128;
  const int cntL = min(128, cnt - mt * 128);
  const int tid = threadIdx.x;
  const int wid = tid >> 6, lane = tid & 63;

  if (tid < 128) s_tok[tid] = row_tok[min(p0 + tid, TT*2 - 1)];
  __syncthreads();

  // A staging sources (glds16, inverse-swizzled source)
  const int sw = (((lane & 7) ^ (lane >> 3)) & 7) << 4;
  const char* asrc[4];
#pragma unroll
  for (int i = 0; i < 4; i++){
    int r = (wid * 4 + i) * 8 + (lane >> 3);                // 0..127
    asrc[i] = (const char*)Xb + (size_t)s_tok[r] * 4096 + sw;
  }
  // B staging: thread -> matrix m2 (0=g,1=u), 4 n x 8 consecutive k
  const int m2 = tid >> 7, tt = tid & 127;
  const int n0 = (tt & 15) * 4;              // 0..60 within 64-col panel
  const int s0 = tt >> 4;                    // k-slot 0..7, k0 = s0*8
  const float* wsrc = (m2 ? Wu : Wg) + (size_t)e * HD * ID
                    + (size_t)(s0 * 8) * ID + (size_t)nt * 64 + n0;
  int bw[4];
#pragma unroll
  for (int j = 0; j < 4; j++){
    int n  = n0 + j;
    int np = (n >> 5) * 64 + (n & 31) + m2 * 32;            // gu-interleaved LDS row
    bw[j] = np * 128 + (((s0 ^ swzB2(np)) & 7) << 4);
  }
  // fragment read offsets
  const int wm = wid >> 1, wn = wid & 1;     // 2x2 waves, wave = 64m x 64n'
  const int kg = lane >> 4, ln = lane & 15;
  int aoff[4], boff[4];
#pragma unroll
  for (int f = 0; f < 4; f++){
    int m = wm * 64 + f * 16 + ln;
    aoff[f] = m * 128 + (((kg ^ (m & 7)) & 7) << 4);
    int n = wn * 64 + f * 16 + ln;
    boff[f] = n * 128 + (((kg ^ swzB2(n)) & 7) << 4);
  }

  f4 acc[4][4];
#pragma unroll
  for (int a = 0; a < 4; a++)
#pragma unroll
    for (int b = 0; b < 4; b++) acc[a][b] = f4{0,0,0,0};

  // prologue: A(0) -> sA[0]; B(0) -> regs
#pragma unroll
  for (int i = 0; i < 4; i++) glds16(asrc[i], &sA[0][0] + (wid * 4 + i) * 1024);
  f4 rk[8];
#pragma unroll
  for (int i = 0; i < 8; i++) rk[i] = *(const f4*)(wsrc + (size_t)i * ID);

  for (int kt = 0; kt < 32; ++kt){
    softbar();                                  // all waves done reading sB(kt-1), sA[alt]
    // ds_write B(kt): dep-wait drains all outstanding loads incl. A(kt) (1 iter old)
#pragma unroll
    for (int j = 0; j < 4; j++){
      *(uint4*)(sB + bw[j]) = uint4{ pk2(rk[0][j], rk[1][j]), pk2(rk[2][j], rk[3][j]),
                                     pk2(rk[4][j], rk[5][j]), pk2(rk[6][j], rk[7][j]) };
    }
    __builtin_amdgcn_sched_barrier(0);
    // glds A(kt+1) -> sA[alt]
    if (kt + 1 < 32){
      const int _o = (kt + 1) * 128;
      char* dst = &sA[(kt + 1) & 1][0] + (wid * 4) * 1024;
#pragma unroll
      for (int i = 0; i < 4; i++) glds16(asrc[i] + _o, dst + i * 1024);
    }
    __builtin_amdgcn_sched_barrier(0);
    // load B(kt+1) regs
    if (kt + 1 < 32){
      const float* p = wsrc + (size_t)(kt + 1) * 64 * ID;
#pragma unroll
      for (int i = 0; i < 8; i++) rk[i] = *(const f4*)(p + (size_t)i * ID);
    }
    __builtin_amdgcn_sched_barrier(0);
    asm volatile("s_waitcnt lgkmcnt(0)" ::: "memory");   // sB(kt) visible; no vmcnt
    __builtin_amdgcn_s_barrier();
    __builtin_amdgcn_sched_barrier(0);
    const char* A = &sA[kt & 1][0];
#pragma unroll
    for (int ks = 0; ks < 2; ks++){
      const int kx = ks * 64;
      short8 af[4], bf[4];
#pragma unroll
      for (int f = 0; f < 4; f++) af[f] = *(const short8*)(A + (aoff[f] ^ kx));
#pragma unroll
      for (int f = 0; f < 4; f++) bf[f] = *(const short8*)(sB + (boff[f] ^ kx));
#pragma unroll
      for (int fn = 0; fn < 4; fn++)
#pragma unroll
        for (int fm = 0; fm < 4; fm++)
          acc[fm][fn] = __builtin_amdgcn_mfma_f32_16x16x32_bf16(af[fm], bf[fn], acc[fm][fn], 0, 0, 0);
    }
  }
  // epilogue: fn 0,1 = g cols, fn 2,3 = u cols of the SAME h columns
#pragma unroll
  for (int fm = 0; fm < 4; fm++){
#pragma unroll
    for (int r = 0; r < 4; r++){
      int row = wm * 64 + fm * 16 + (lane >> 4) * 4 + r;
      if (row < cntL){
        size_t base = (size_t)(p0 + row) * ID + (size_t)nt * 64 + wn * 32 + ln;
#pragma unroll
        for (int fn = 0; fn < 2; fn++){
          float g = acc[fm][fn][r];
          float u = acc[fm][fn + 2][r];
          hbuf[base + fn * 16] = __float2bfloat16(gelu_t(g) * u);
        }
      }
    }
  }
}

// -------- down: fused fp32 Wd staging + weighted atomic scatter --------
__global__ __launch_bounds__(256, 3)
void k_dn_f(const __hip_bfloat16* __restrict__ hbuf, const float* __restrict__ Wd,
            const int* __restrict__ row_tok, const float* __restrict__ row_w,
            const int* __restrict__ off, float* __restrict__ out){
  __shared__ __align__(16) char sA[2][16384];  // [128 m][64 k], dbuf
  __shared__ __align__(16) char sB[16384];     // [128 n][64 k], slot^=swzB2(n)
  __shared__ int s_tok[128];
  __shared__ float s_w[128];

  const int bid = blockIdx.x;                // 640 = e(bid&7) x 5mt x 16nt
  const int e  = bid & 7;
  const int t  = bid >> 3;
  const int mt = t % 5;
  const int nt = t / 5;                      // 0..15
  const int o0 = off[e], cnt = off[e + 1] - o0;
  if (mt * 128 >= cnt) return;
  const int p0 = o0 + mt * 128;
  const int cntL = min(128, cnt - mt * 128);
  const int tid = threadIdx.x;
  const int wid = tid >> 6, lane = tid & 63;

  if (tid < 128){
    int p = min(p0 + tid, TT*2 - 1);
    s_tok[tid] = row_tok[p];
    s_w[tid]   = row_w[p];
  }
  __syncthreads();

  const int sw = (((lane & 7) ^ (lane >> 3)) & 7) << 4;
  const char* asrc[4];
#pragma unroll
  for (int i = 0; i < 4; i++){
    int r = (wid * 4 + i) * 8 + (lane >> 3);
    int p = min(p0 + r, TT*2 - 1);
    asrc[i] = (const char*)hbuf + (size_t)p * 4096 + sw;
  }
  // B staging: thread -> 4 n x 8 consecutive k of Wd [k][HD n]
  const int n0 = (tid & 31) * 4;             // 0..124
  const int s0 = tid >> 5;                   // 0..7, k0 = s0*8
  const float* wsrc = Wd + (size_t)e * ID * HD + (size_t)(s0 * 8) * HD + (size_t)nt * 128 + n0;
  int bw[4];
#pragma unroll
  for (int j = 0; j < 4; j++){
    int np = n0 + j;
    bw[j] = np * 128 + (((s0 ^ swzB2(np)) & 7) << 4);
  }
  const int wm = wid >> 1, wn = wid & 1;
  const int kg = lane >> 4, ln = lane & 15;
  int aoff[4], boff[4];
#pragma unroll
  for (int f = 0; f < 4; f++){
    int m = wm * 64 + f * 16 + ln;
    aoff[f] = m * 128 + (((kg ^ (m & 7)) & 7) << 4);
    int n = wn * 64 + f * 16 + ln;
    boff[f] = n * 128 + (((kg ^ swzB2(n)) & 7) << 4);
  }

  f4 acc[4][4];
#pragma unroll
  for (int a = 0; a < 4; a++)
#pragma unroll
    for (int b = 0; b < 4; b++) acc[a][b] = f4{0,0,0,0};

#pragma unroll
  for (int i = 0; i < 4; i++) glds16(asrc[i], &sA[0][0] + (wid * 4 + i) * 1024);
  f4 rk[8];
#pragma unroll
  for (int i = 0; i < 8; i++) rk[i] = *(const f4*)(wsrc + (size_t)i * HD);

  for (int kt = 0; kt < 32; ++kt){
    softbar();
#pragma unroll
    for (int j = 0; j < 4; j++){
      *(uint4*)(sB + bw[j]) = uint4{ pk2(rk[0][j], rk[1][j]), pk2(rk[2][j], rk[3][j]),
                                     pk2(rk[4][j], rk[5][j]), pk2(rk[6][j], rk[7][j]) };
    }
    __builtin_amdgcn_sched_barrier(0);
    if (kt + 1 < 32){
      const int _o = (kt + 1) * 128;
      char* dst = &sA[(kt + 1) & 1][0] + (wid * 4) * 1024;
#pragma unroll
      for (int i = 0; i < 4; i++) glds16(asrc[i] + _o, dst + i * 1024);
    }
    __builtin_amdgcn_sched_barrier(0);
    if (kt + 1 < 32){
      const float* p = wsrc + (size_t)(kt + 1) * 64 * HD;
#pragma unroll
      for (int i = 0; i < 8; i++) rk[i] = *(const f4*)(p + (size_t)i * HD);
    }
    __builtin_amdgcn_sched_barrier(0);
    asm volatile("s_waitcnt lgkmcnt(0)" ::: "memory");
    __builtin_amdgcn_s_barrier();
    __builtin_amdgcn_sched_barrier(0);
    const char* A = &sA[kt & 1][0];
#pragma unroll
    for (int ks = 0; ks < 2; ks++){
      const int kx = ks * 64;
      short8 af[4], bf[4];
#pragma unroll
      for (int f = 0; f < 4; f++) af[f] = *(const short8*)(A + (aoff[f] ^ kx));
#pragma unroll
      for (int f = 0; f < 4; f++) bf[f] = *(const short8*)(sB + (boff[f] ^ kx));
#pragma unroll
      for (int fn = 0; fn < 4; fn++)
#pragma unroll
        for (int fm = 0; fm < 4; fm++)
          acc[fm][fn] = __builtin_amdgcn_mfma_f32_16x16x32_bf16(af[fm], bf[fn], acc[fm][fn], 0, 0, 0);
    }
  }
#pragma unroll
  for (int fm = 0; fm < 4; fm++){
#pragma unroll
    for (int r = 0; r < 4; r++){
      int row = wm * 64 + fm * 16 + (lane >> 4) * 4 + r;
      if (row < cntL){
        int tok = s_tok[row];
        float w = s_w[row];
        float* ob = out + (size_t)tok * HD + (size_t)nt * 128 + wn * 64 + ln;
#pragma unroll
        for (int fn = 0; fn < 4; fn++)
          atomicAdd(ob + fn * 16, acc[fm][fn][r] * w);
      }
    }
  }
}

extern "C" void kernel_launch(void* const* d_in, const int* in_sizes, int n_in,
                              void* d_out, int out_size, void* d_ws, size_t ws_size,
                              hipStream_t stream){
  (void)in_sizes; (void)n_in; (void)out_size; (void)ws_size;
  const float* X  = (const float*)d_in[0];
  const float* RL = (const float*)d_in[1];
  const float* SC = (const float*)d_in[2];
  const float* Wg = (const float*)d_in[3];
  const float* Wu = (const float*)d_in[4];
  const float* Wd = (const float*)d_in[5];
  float* out = (float*)d_out;

  char* ws = (char*)d_ws;
  int*   rid     = (int*)(ws);
  float* rw      = (float*)(ws + 16384);
  int*   row_tok = (int*)(ws + 32768);
  float* row_w   = (float*)(ws + 49152);
  int*   off     = (int*)(ws + 65536);
  __hip_bfloat16* hbuf = (__hip_bfloat16*)(ws + 66560);                      // 16 MiB
  __hip_bfloat16* Xb   = (__hip_bfloat16*)(ws + 66560 + 16777216ull);        // 8 MiB

  hipMemsetAsync(d_out, 0, (size_t)TT * HD * sizeof(float), stream);
  k_cvtx <<<2048, 256, 0, stream>>>(X, Xb);
  k_route<<<TT / 256, 256, 0, stream>>>(RL, SC, rid, rw);
  k_lists<<<1, 64, 0, stream>>>(rid, rw, row_tok, row_w, off);
  k_gu_f<<<1280, 256, 0, stream>>>(Xb, Wg, Wu, row_tok, off, hbuf);
  k_dn_f<<< 640, 256, 0, stream>>>(hbuf, Wd, row_tok, row_w, off, out);
}